// Round 8
// baseline (259.802 us; speedup 1.0000x reference)
//
#include <hip/hip_runtime.h>
#include <hip/hip_bf16.h>
#include <stdint.h>

typedef __bf16 bf16x8 __attribute__((ext_vector_type(8)));
typedef __bf16 bf16x4 __attribute__((ext_vector_type(4)));
typedef float  f32x4  __attribute__((ext_vector_type(4)));
typedef unsigned int u32x4 __attribute__((ext_vector_type(4)));

#define D_MODEL 1024
#define NUM_HEADS 16
#define D_K 64
#define BATCH 2
#define SEQ 2048
#define M_TOTAL (BATCH * SEQ)   // 4096

// 0.125 (1/sqrt(64)) * log2(e): folded into Q at the qkv epilogue so the
// attention softmax is a bare exp2 (v_exp_f32), no per-element scale mul.
#define Q_SCALE 0.18033688011112042f

static __device__ __forceinline__ bf16x8 load8(const __bf16* p) {
    return *reinterpret_cast<const bf16x8*>(p);
}

#define MFMA16(a, b, c) __builtin_amdgcn_mfma_f32_16x16x32_bf16((a), (b), (c), 0, 0, 0)

// Async global->LDS, 16B per lane. LDS dest = wave-uniform base + lane*16.
static __device__ __forceinline__ void gload16(const void* g, const void* lds) {
    __builtin_amdgcn_global_load_lds(
        (const __attribute__((address_space(1))) uint32_t*)g,
        (__attribute__((address_space(3))) uint32_t*)lds,
        16, 0, 0);
}

// Pack two f32 -> one u32 of 2 bf16 (lo = first arg). No builtin on gfx950.
static __device__ __forceinline__ uint32_t cvtpk(float lo, float hi) {
    uint32_t r;
    asm("v_cvt_pk_bf16_f32 %0, %1, %2" : "=v"(r) : "v"(lo), "v"(hi));
    return r;
}
// CDNA4 zip semantics ("DST rows 2:3 <-> SRC rows 0:1", rows = 16 lanes):
//   swap32: a' = (a@q0, a@q1, b@q0, b@q1), b' = (a@q2, a@q3, b@q2, b@q3)
static __device__ __forceinline__ void swap32(uint32_t& a, uint32_t& b) {
    asm("v_permlane32_swap_b32 %0, %1" : "+v"(a), "+v"(b));
}
// swap16 ("DST odd rows <-> SRC even rows"):
//   a' = (a@q0, b@q0, a@q2, b@q2), b' = (a@q1, b@q1, a@q3, b@q3)
static __device__ __forceinline__ void swap16(uint32_t& a, uint32_t& b) {
    asm("v_permlane16_swap_b32 %0, %1" : "+v"(a), "+v"(b));
}

// ---------------------------------------------------------------------------
// One launch: x (2048 blocks) + 4 weight matrices (512 blocks each) fp32->bf16.
// ---------------------------------------------------------------------------
__global__ __launch_bounds__(256) void convert_all(
    const float* __restrict__ X,
    const float* __restrict__ Wq, const float* __restrict__ Wk,
    const float* __restrict__ Wv, const float* __restrict__ Wo,
    __bf16* __restrict__ xb,
    __bf16* __restrict__ dq, __bf16* __restrict__ dk,
    __bf16* __restrict__ dv, __bf16* __restrict__ dw)
{
    const float* src; __bf16* dst; size_t idx;
    if (blockIdx.x < 2048) {
        src = X; dst = xb;
        idx = (size_t)blockIdx.x * 256 + threadIdx.x;
    } else {
        const int wb  = blockIdx.x - 2048;
        const int sel = wb >> 9;
        src = (sel == 0) ? Wq : (sel == 1) ? Wk : (sel == 2) ? Wv : Wo;
        dst = (sel == 0) ? dq : (sel == 1) ? dk : (sel == 2) ? dv : dw;
        idx = (size_t)(wb & 511) * 256 + threadIdx.x;
    }
    const f32x4 a = *reinterpret_cast<const f32x4*>(src + idx * 8);
    const f32x4 b = *reinterpret_cast<const f32x4*>(src + idx * 8 + 4);
    bf16x8 r;
#pragma unroll
    for (int e = 0; e < 4; e++) { r[e] = (__bf16)a[e]; r[4 + e] = (__bf16)b[e]; }
    *reinterpret_cast<bf16x8*>(dst + idx * 8) = r;
}

// ---------------------------------------------------------------------------
// QKV GEMM: 128x128 tile, BK=64, swizzled gload16 staging, double-buffered
// prefetch loop (one barrier per K-step, next tile's loads in flight through
// compute). LDS 64 KB -> 2 blocks/CU. Q output pre-scaled by Q_SCALE.
// V output transposed through LDS -> coalesced V^T. grid = (32, 24).
// ---------------------------------------------------------------------------
__global__ __launch_bounds__(256) void qkv_kernel(
    const __bf16* __restrict__ Xb,
    const __bf16* __restrict__ Wqb,
    const __bf16* __restrict__ Wkb,
    const __bf16* __restrict__ Wvb,
    __bf16* __restrict__ Qb,
    __bf16* __restrict__ Kb,
    __bf16* __restrict__ Vtg)
{
    __shared__ alignas(16) char smem[65536];   // A[2]16K + B[2]16K; V scratch 34K
    __bf16* As0 = (__bf16*)smem;               // [2][128*64], chunk-swizzled
    __bf16* Bs0 = As0 + 2 * 128 * 64;

    const int lane = threadIdx.x & 63;
    const int wid  = threadIdx.x >> 6;
    const int m    = lane & 15;
    const int quad = lane >> 4;
    const int wrow = wid >> 1, wcol = wid & 1;
    const int row0 = blockIdx.x * 128;
    const int col0 = blockIdx.y * 128;
    const int wsel = col0 >> 10;
    const int lcol0 = col0 & 1023;

    const __bf16* W = (wsel == 0) ? Wqb : (wsel == 1) ? Wkb : Wvb;

    // staging: 128x64 A-tile + 128x64 B-tile into buffer `buf`
    auto stage = [&](int k0, int buf) {
#pragma unroll
        for (int i = 0; i < 4; i++) {
            const int slot = wid * 256 + i * 64 + lane;
            const int row  = slot >> 3;
            const int cg   = (slot & 7) ^ (row & 7);
            gload16(Xb + (size_t)(row0 + row) * D_MODEL + k0 + cg * 8,
                    (const char*)(As0 + buf * 8192) + (size_t)(wid * 256 + i * 64) * 16);
            gload16(W + (size_t)(lcol0 + row) * D_MODEL + k0 + cg * 8,
                    (const char*)(Bs0 + buf * 8192) + (size_t)(wid * 256 + i * 64) * 16);
        }
    };

    f32x4 acc[4][4];
#pragma unroll
    for (int i = 0; i < 4; i++)
#pragma unroll
        for (int j = 0; j < 4; j++) acc[i][j] = (f32x4){0.f, 0.f, 0.f, 0.f};

    stage(0, 0);
    int cur = 0;
#pragma unroll 1
    for (int k0 = 0; k0 < D_MODEL; k0 += 64) {
        __syncthreads();                       // buffer `cur` staged
        if (k0 + 64 < D_MODEL) stage(k0 + 64, cur ^ 1);   // in flight through
                                                          // compute below
        const __bf16* As = As0 + cur * 8192;
        const __bf16* Bs = Bs0 + cur * 8192;

        bf16x8 a2[2][4], b2[2][4];
#pragma unroll
        for (int ks = 0; ks < 2; ks++) {
#pragma unroll
            for (int i = 0; i < 4; i++) {
                const int rA = wrow * 64 + i * 16 + m;
                a2[ks][i] = load8(As + rA * 64 + (((ks * 4 + quad) ^ (rA & 7)) * 8));
                const int rB = wcol * 64 + i * 16 + m;
                b2[ks][i] = load8(Bs + rB * 64 + (((ks * 4 + quad) ^ (rB & 7)) * 8));
            }
        }
#pragma unroll
        for (int ks = 0; ks < 2; ks++)
#pragma unroll
            for (int i = 0; i < 4; i++)
#pragma unroll
                for (int j = 0; j < 4; j++)
                    acc[i][j] = MFMA16(a2[ks][i], b2[ks][j], acc[i][j]);
        cur ^= 1;
    }
    __syncthreads();   // all LDS reads done before V-path smem reuse

    if (wsel < 2) {
        // Q (pre-scaled) / K: [bh][s][dk]
        __bf16* Out = wsel ? Kb : Qb;
        const float sc = wsel ? 1.f : Q_SCALE;
#pragma unroll
        for (int i = 0; i < 4; i++) {
#pragma unroll
            for (int r = 0; r < 4; r++) {
                const int R  = row0 + wrow * 64 + i * 16 + quad * 4 + r;
                const int bb = R >> 11;
                const int s  = R & (SEQ - 1);
#pragma unroll
                for (int j = 0; j < 4; j++) {
                    const int e  = lcol0 + wcol * 64 + j * 16 + m;
                    const int h  = e >> 6;
                    const int dk = e & (D_K - 1);
                    Out[((size_t)(bb * NUM_HEADS + h) * SEQ + s) * D_K + dk] =
                        (__bf16)(acc[i][j][r] * sc);
                }
            }
        }
    } else {
        // V: transpose tile through LDS, store coalesced V^T rows.
        __bf16* Ls = (__bf16*)smem;   // [128][136]
#pragma unroll
        for (int i = 0; i < 4; i++)
#pragma unroll
            for (int r = 0; r < 4; r++)
#pragma unroll
                for (int j = 0; j < 4; j++)
                    Ls[(wcol * 64 + j * 16 + m) * 136 +
                       wrow * 64 + i * 16 + quad * 4 + r] = (__bf16)acc[i][j][r];
        __syncthreads();
        const int bb   = row0 >> 11;
        const int sloc = row0 & (SEQ - 1);
#pragma unroll
        for (int i = 0; i < 8; i++) {
            const int c   = i * 256 + threadIdx.x;
            const int dkl = c >> 4;
            const int sc  = c & 15;
            const bf16x8 v = load8(Ls + dkl * 136 + sc * 8);
            const int e  = lcol0 + dkl;
            const int h  = e >> 6;
            const int dk = e & (D_K - 1);
            const int bh = bb * NUM_HEADS + h;
            *reinterpret_cast<bf16x8*>(
                Vtg + ((size_t)bh * D_K + dk) * SEQ + sloc + sc * 8) = v;
        }
    }
}

// ---------------------------------------------------------------------------
// Flash attention, causal. R18: ZERO-LDS, ZERO-BARRIER -- K/V fragments are
// read DIRECTLY from global. Per XCD, resident blocks are bh = xcd (mod 8)
// -> 4 heads x 512 KB = 2 MB working set, fits the 4 MB per-XCD L2; the 4
// waves of a block read the same 16 KB tile -> L1 absorbs the redundancy
// (Common-mistake #7 / m169: dropping L2-fit staging was +26% on attn).
// Removes: gload16 staging, double-buffer, swizzle VALU, all __syncthreads
// and their vmcnt drains. Waves run fully independent; V-fragment loads
// hoisted to tile-top so their latency hides under QK+exp+permlane.
// QBLK=64, grid (32 bh, 32 strips), 1024 blocks = 4/CU. Register-resident
// P (zip-permlane), ones-MFMA row sums, setprio around MFMA clusters.
// ---------------------------------------------------------------------------
__global__ __launch_bounds__(256) void attn_kernel(
    const __bf16* __restrict__ Qb,
    const __bf16* __restrict__ Kb,
    const __bf16* __restrict__ Vtg,
    __bf16* __restrict__ Cc)
{
    const int lane = threadIdx.x & 63;
    const int wid  = threadIdx.x >> 6;
    const int m    = lane & 15;
    const int quad = lane >> 4;
    const int bh   = blockIdx.x;
    const int b    = bh >> 4;
    const int h    = bh & (NUM_HEADS - 1);
    // balanced strip map (R17): per-CU strip-length sums equal, big first
    const int y    = blockIdx.y;
    const int g    = y >> 3;
    const int o    = y & 7;
    const int s    = (g == 0) ? 31 - o : (g == 1) ? o : (g == 2) ? 23 - o : 8 + o;

    const __bf16* Qp = Qb  + (size_t)bh * SEQ * D_K;
    const __bf16* Kp = Kb  + (size_t)bh * SEQ * D_K;
    const __bf16* Vp = Vtg + (size_t)bh * D_K * SEQ;

    bf16x8 vone;
#pragma unroll
    for (int e = 0; e < 8; e++) vone[e] = (__bf16)1.0f;

    const int q0 = s * 64 + wid * 16;              // this wave's 16 q rows

    const bf16x8 qB0 = load8(Qp + (size_t)(q0 + m) * D_K + quad * 8);
    const bf16x8 qB1 = load8(Qp + (size_t)(q0 + m) * D_K + 32 + quad * 8);

    f32x4 oacc[4];
#pragma unroll
    for (int c = 0; c < 4; c++) oacc[c] = (f32x4){0.f, 0.f, 0.f, 0.f};
    f32x4 accL = (f32x4){0.f, 0.f, 0.f, 0.f};      // l for q = q0+quad*4+r

#pragma unroll 1
    for (int t = 0; t <= s; t++) {
        const bool diag = (t == s);
        const int  k0   = t * 64;

        // ---- V fragments first: longest latency, consumed last ----
        bf16x8 vfA[4], vfB[4];
#pragma unroll
        for (int c = 0; c < 4; c++) {
            const int rV = c * 16 + m;
            vfA[c] = load8(Vp + (size_t)rV * SEQ + k0 + quad * 8);
            vfB[c] = load8(Vp + (size_t)rV * SEQ + k0 + 32 + quad * 8);
        }

        // ---- S^T = K Q^T (rows=keys, cols=q); exp2; pack to bf16 words.
        // Lane (m,quad) produces keys {kb*16+quad*4 .. +3} for q=q0+m:
        // w0[kb] = keys {4*quad, 4*quad+1}, w1[kb] = {4*quad+2, 4*quad+3}.
        uint32_t w0[4], w1[4];
#pragma unroll
        for (int kb = 0; kb < 4; kb++) {
            const int rK = kb * 16 + m;
            const bf16x8 kfA = load8(Kp + (size_t)(k0 + rK) * D_K + quad * 8);
            const bf16x8 kfB = load8(Kp + (size_t)(k0 + rK) * D_K + 32 + quad * 8);
            f32x4 st = (f32x4){0.f, 0.f, 0.f, 0.f};
            __builtin_amdgcn_s_setprio(1);
            st = MFMA16(kfA, qB0, st);
            st = MFMA16(kfB, qB1, st);
            __builtin_amdgcn_s_setprio(0);
            const int q    = q0 + m;
            const int keyb = k0 + kb * 16 + quad * 4;
            float ex[4];
#pragma unroll
            for (int r = 0; r < 4; r++) {
                float e = __builtin_amdgcn_exp2f(st[r]);
                if (diag) e = (keyb + r <= q) ? e : 0.f;
                ex[r] = e;
            }
            w0[kb] = cvtpk(ex[0], ex[1]);
            w1[kb] = cvtpk(ex[2], ex[3]);
        }

        // ---- redistribute to A-fragments (keys 8*quad..+7 per lane).
        // Zip semantics, verified key-by-key:
        //   (X=w[lo], Y=w[hi]); swap32; swap16 => X=word j, Y=word j+2.
        uint32_t pa0 = w0[0], pa2 = w0[1]; swap32(pa0, pa2); swap16(pa0, pa2);
        uint32_t pa1 = w1[0], pa3 = w1[1]; swap32(pa1, pa3); swap16(pa1, pa3);
        uint32_t pb0 = w0[2], pb2 = w0[3]; swap32(pb0, pb2); swap16(pb0, pb2);
        uint32_t pb1 = w1[2], pb3 = w1[3]; swap32(pb1, pb3); swap16(pb1, pb3);
        const u32x4 ua = (u32x4){pa0, pa1, pa2, pa3};
        const u32x4 ub = (u32x4){pb0, pb1, pb2, pb3};
        const bf16x8 pfA = __builtin_bit_cast(bf16x8, ua);
        const bf16x8 pfB = __builtin_bit_cast(bf16x8, ub);

        // ---- row-sum via ones-MFMA + P.V (MFMA cluster, setprio-wrapped) --
        __builtin_amdgcn_s_setprio(1);
        accL = MFMA16(pfA, vone, accL);
        accL = MFMA16(pfB, vone, accL);
#pragma unroll
        for (int c = 0; c < 4; c++) {
            oacc[c] = MFMA16(pfA, vfA[c], oacc[c]);
            oacc[c] = MFMA16(pfB, vfB[c], oacc[c]);
        }
        __builtin_amdgcn_s_setprio(0);
    }

    // ---- epilogue: l is already per-register in accL ----
#pragma unroll
    for (int r = 0; r < 4; r++) {
        const float inv = 1.f / accL[r];
        const int srow = q0 + quad * 4 + r;
#pragma unroll
        for (int c = 0; c < 4; c++) {
            const size_t o2 = ((size_t)(b * SEQ + srow)) * D_MODEL + h * D_K + c * 16 + m;
            Cc[o2] = (__bf16)(oacc[c][r] * inv);
        }
    }
}

// ---------------------------------------------------------------------------
// Output projection: Out = Cc * Wo^T + bo (fp32). 64x64 tile, grid (64,16)
// = 1024 blocks = 4/CU, double-buffered prefetch loop (one barrier/K-step).
// ---------------------------------------------------------------------------
__global__ __launch_bounds__(256) void oproj_kernel(
    const __bf16* __restrict__ Cc,
    const __bf16* __restrict__ Wob,
    const float* __restrict__ bo,
    float* __restrict__ Out)
{
    __shared__ alignas(16) __bf16 As[2][64 * 64];  // ping-pong, 8 KB each
    __shared__ alignas(16) __bf16 Bs[2][64 * 64];  // ping-pong, 8 KB each

    const int lane = threadIdx.x & 63;
    const int wid  = threadIdx.x >> 6;
    const int m    = lane & 15;
    const int quad = lane >> 4;
    const int wrow = wid >> 1, wcol = wid & 1;
    const int row0 = blockIdx.x * 64;
    const int col0 = blockIdx.y * 64;

    auto stage = [&](int k0, int buf) {
#pragma unroll
        for (int i = 0; i < 2; i++) {
            const int slot = wid * 128 + i * 64 + lane;
            const int row  = slot >> 3;
            const int cg   = (slot & 7) ^ (row & 7);
            gload16(Cc + (size_t)(row0 + row) * D_MODEL + k0 + cg * 8,
                    (const char*)&As[buf][0] + (size_t)(wid * 128 + i * 64) * 16);
            gload16(Wob + (size_t)(col0 + row) * D_MODEL + k0 + cg * 8,
                    (const char*)&Bs[buf][0] + (size_t)(wid * 128 + i * 64) * 16);
        }
    };

    f32x4 acc[2][2];
#pragma unroll
    for (int i = 0; i < 2; i++)
#pragma unroll
        for (int j = 0; j < 2; j++) acc[i][j] = (f32x4){0.f, 0.f, 0.f, 0.f};

    stage(0, 0);
    int cur = 0;
#pragma unroll 1
    for (int k0 = 0; k0 < D_MODEL; k0 += 64) {
        __syncthreads();                       // buffer `cur` staged
        if (k0 + 64 < D_MODEL) stage(k0 + 64, cur ^ 1);

        bf16x8 a2[2][2], b2[2][2];
#pragma unroll
        for (int ks = 0; ks < 2; ks++) {
#pragma unroll
            for (int i = 0; i < 2; i++) {
                const int rA = wrow * 32 + i * 16 + m;
                a2[ks][i] = load8(&As[cur][0] + rA * 64 + (((ks * 4 + quad) ^ (rA & 7)) * 8));
                const int rB = wcol * 32 + i * 16 + m;
                b2[ks][i] = load8(&Bs[cur][0] + rB * 64 + (((ks * 4 + quad) ^ (rB & 7)) * 8));
            }
        }
#pragma unroll
        for (int ks = 0; ks < 2; ks++)
#pragma unroll
            for (int i = 0; i < 2; i++)
#pragma unroll
                for (int j = 0; j < 2; j++)
                    acc[i][j] = MFMA16(a2[ks][i], b2[ks][j], acc[i][j]);
        cur ^= 1;
    }

#pragma unroll
    for (int i = 0; i < 2; i++) {
#pragma unroll
        for (int r = 0; r < 4; r++) {
            const int R = row0 + wrow * 32 + i * 16 + quad * 4 + r;
#pragma unroll
            for (int j = 0; j < 2; j++) {
                const int E = col0 + wcol * 32 + j * 16 + m;
                Out[(size_t)R * D_MODEL + E] = acc[i][j][r] + bo[E];
            }
        }
    }
}

// ---------------------------------------------------------------------------
extern "C" void kernel_launch(void* const* d_in, const int* in_sizes, int n_in,
                              void* d_out, int out_size, void* d_ws, size_t ws_size,
                              hipStream_t stream) {
    const float* x  = (const float*)d_in[0];
    const float* Wq = (const float*)d_in[1];
    const float* Wk = (const float*)d_in[2];
    const float* Wv = (const float*)d_in[3];
    const float* Wo = (const float*)d_in[4];
    const float* bo = (const float*)d_in[5];
    // d_in[6] = causal mask — recomputed from indices, not read.

    const size_t elems  = (size_t)M_TOTAL * D_MODEL;   // 4194304
    const size_t welems = (size_t)D_MODEL * D_MODEL;   // 1048576
    __bf16* xb  = (__bf16*)d_ws;       // seg0: x (bf16) -> later Cc (aliased)
    __bf16* Qb  = xb + elems;
    __bf16* Kb  = Qb + elems;
    __bf16* Vtg = Kb + elems;          // [32][64][2048]  (V^T)
    __bf16* Wqb = Vtg + elems;
    __bf16* Wkb = Wqb + welems;
    __bf16* Wvb = Wkb + welems;
    __bf16* Wob = Wvb + welems;        // end: 40 MB
    __bf16* Cc  = xb;

    // 0) all fp32 -> bf16 conversions in one launch
    convert_all<<<dim3(4096), 256, 0, stream>>>(
        x, Wq, Wk, Wv, Wo, xb, Wqb, Wkb, Wvb, Wob);

    // 1) QKV projections (Q pre-scaled by 0.125*log2e), dbuf prefetch loop
    qkv_kernel<<<dim3(M_TOTAL / 128, 3 * D_MODEL / 128), 256, 0, stream>>>(
        xb, Wqb, Wkb, Wvb, Qb, Kb, Vtg);

    // 2) causal flash attention: zero-LDS, zero-barrier, direct-L2 fragments
    attn_kernel<<<dim3(BATCH * NUM_HEADS, 32), 256, 0, stream>>>(
        Qb, Kb, Vtg, Cc);

    // 3) output projection + bias -> fp32 out (64x64 tiles, dbuf prefetch)
    oproj_kernel<<<dim3(M_TOTAL / 64, D_MODEL / 64), 256, 0, stream>>>(
        Cc, Wob, bo, (float*)d_out);
}

// Round 9
// 227.497 us; speedup vs baseline: 1.1420x; 1.1420x over previous
//
#include <hip/hip_runtime.h>
#include <hip/hip_bf16.h>
#include <stdint.h>

typedef __bf16 bf16x8 __attribute__((ext_vector_type(8)));
typedef __bf16 bf16x4 __attribute__((ext_vector_type(4)));
typedef float  f32x4  __attribute__((ext_vector_type(4)));
typedef unsigned int u32x4 __attribute__((ext_vector_type(4)));

#define D_MODEL 1024
#define NUM_HEADS 16
#define D_K 64
#define BATCH 2
#define SEQ 2048
#define M_TOTAL (BATCH * SEQ)   // 4096

// 0.125 (1/sqrt(64)) * log2(e): folded into Q at the qkv epilogue so the
// attention softmax is a bare exp2 (v_exp_f32), no per-element scale mul.
#define Q_SCALE 0.18033688011112042f

static __device__ __forceinline__ bf16x8 load8(const __bf16* p) {
    return *reinterpret_cast<const bf16x8*>(p);
}

#define MFMA16(a, b, c) __builtin_amdgcn_mfma_f32_16x16x32_bf16((a), (b), (c), 0, 0, 0)

// Async global->LDS, 16B per lane. LDS dest = wave-uniform base + lane*16.
static __device__ __forceinline__ void gload16(const void* g, const void* lds) {
    __builtin_amdgcn_global_load_lds(
        (const __attribute__((address_space(1))) uint32_t*)g,
        (__attribute__((address_space(3))) uint32_t*)lds,
        16, 0, 0);
}

// Pack two f32 -> one u32 of 2 bf16 (lo = first arg). No builtin on gfx950.
static __device__ __forceinline__ uint32_t cvtpk(float lo, float hi) {
    uint32_t r;
    asm("v_cvt_pk_bf16_f32 %0, %1, %2" : "=v"(r) : "v"(lo), "v"(hi));
    return r;
}
// CDNA4 zip semantics ("DST rows 2:3 <-> SRC rows 0:1", rows = 16 lanes):
//   swap32: a' = (a@q0, a@q1, b@q0, b@q1), b' = (a@q2, a@q3, b@q2, b@q3)
static __device__ __forceinline__ void swap32(uint32_t& a, uint32_t& b) {
    asm("v_permlane32_swap_b32 %0, %1" : "+v"(a), "+v"(b));
}
// swap16 ("DST odd rows <-> SRC even rows"):
//   a' = (a@q0, b@q0, a@q2, b@q2), b' = (a@q1, b@q1, a@q3, b@q3)
static __device__ __forceinline__ void swap16(uint32_t& a, uint32_t& b) {
    asm("v_permlane16_swap_b32 %0, %1" : "+v"(a), "+v"(b));
}

// ---------------------------------------------------------------------------
// QKV GEMM, R19: reads fp32 X and fp32 weights DIRECTLY (convert kernel
// eliminated -> 4 launches become 3). Staging is reg-path convert-on-the-fly
// (T14 split): global_load fp32 pairs for tile k+1 issued right after the
// barrier (latency hides under tile k's MFMA), then cvt+ds_write_b128 into
// the other buffer, ONE barrier per K-step. The LDS image written is byte-
// identical to what gload16 wrote before, so fragment reads/MFMA/epilogue
// are unchanged. 128x128 tile, BK=64, LDS 64 KB dbuf -> 2 blocks/CU.
// Q output pre-scaled by Q_SCALE. V transposed through LDS -> V^T.
// grid = (32, 24), block = 256.
// ---------------------------------------------------------------------------
__global__ __launch_bounds__(256) void qkv_kernel(
    const float* __restrict__ Xf,
    const float* __restrict__ Wqf,
    const float* __restrict__ Wkf,
    const float* __restrict__ Wvf,
    __bf16* __restrict__ Qb,
    __bf16* __restrict__ Kb,
    __bf16* __restrict__ Vtg)
{
    __shared__ alignas(16) char smem[65536];   // A[2]16K + B[2]16K; V scratch 34K
    __bf16* As0 = (__bf16*)smem;               // [2][128*64], chunk-swizzled
    __bf16* Bs0 = As0 + 2 * 128 * 64;

    const int lane = threadIdx.x & 63;
    const int wid  = threadIdx.x >> 6;
    const int m    = lane & 15;
    const int quad = lane >> 4;
    const int wrow = wid >> 1, wcol = wid & 1;
    const int row0 = blockIdx.x * 128;
    const int col0 = blockIdx.y * 128;
    const int wsel = col0 >> 10;
    const int lcol0 = col0 & 1023;

    const float* W = (wsel == 0) ? Wqf : (wsel == 1) ? Wkf : Wvf;

    // staged fp32 registers for one K-step (issued early, written late)
    f32x4 ra[4][2], rb[4][2];

    auto stage_load = [&](int k0) {
#pragma unroll
        for (int i = 0; i < 4; i++) {
            const int slot = wid * 256 + i * 64 + lane;
            const int row  = slot >> 3;
            const int cg   = (slot & 7) ^ (row & 7);
            const float* pa = Xf + (size_t)(row0 + row) * D_MODEL + k0 + cg * 8;
            const float* pb = W  + (size_t)(lcol0 + row) * D_MODEL + k0 + cg * 8;
            ra[i][0] = *reinterpret_cast<const f32x4*>(pa);
            ra[i][1] = *reinterpret_cast<const f32x4*>(pa + 4);
            rb[i][0] = *reinterpret_cast<const f32x4*>(pb);
            rb[i][1] = *reinterpret_cast<const f32x4*>(pb + 4);
        }
    };
    auto stage_write = [&](int buf) {
#pragma unroll
        for (int i = 0; i < 4; i++) {
            const int slot = wid * 256 + i * 64 + lane;
            bf16x8 va, vb;
#pragma unroll
            for (int e = 0; e < 4; e++) {
                va[e] = (__bf16)ra[i][0][e]; va[4 + e] = (__bf16)ra[i][1][e];
                vb[e] = (__bf16)rb[i][0][e]; vb[4 + e] = (__bf16)rb[i][1][e];
            }
            *reinterpret_cast<bf16x8*>((char*)(As0 + buf * 8192) + (size_t)slot * 16) = va;
            *reinterpret_cast<bf16x8*>((char*)(Bs0 + buf * 8192) + (size_t)slot * 16) = vb;
        }
    };

    f32x4 acc[4][4];
#pragma unroll
    for (int i = 0; i < 4; i++)
#pragma unroll
        for (int j = 0; j < 4; j++) acc[i][j] = (f32x4){0.f, 0.f, 0.f, 0.f};

    stage_load(0);
    stage_write(0);
    int cur = 0;
#pragma unroll 1
    for (int k0 = 0; k0 < D_MODEL; k0 += 64) {
        __syncthreads();                       // buffer `cur` visible to all
        const bool nxt = (k0 + 64 < D_MODEL);
        if (nxt) stage_load(k0 + 64);          // fp32 loads in flight through
                                               // the compute below
        const __bf16* As = As0 + cur * 8192;
        const __bf16* Bs = Bs0 + cur * 8192;

        bf16x8 a2[2][4], b2[2][4];
#pragma unroll
        for (int ks = 0; ks < 2; ks++) {
#pragma unroll
            for (int i = 0; i < 4; i++) {
                const int rA = wrow * 64 + i * 16 + m;
                a2[ks][i] = load8(As + rA * 64 + (((ks * 4 + quad) ^ (rA & 7)) * 8));
                const int rB = wcol * 64 + i * 16 + m;
                b2[ks][i] = load8(Bs + rB * 64 + (((ks * 4 + quad) ^ (rB & 7)) * 8));
            }
        }
#pragma unroll
        for (int ks = 0; ks < 2; ks++)
#pragma unroll
            for (int i = 0; i < 4; i++)
#pragma unroll
                for (int j = 0; j < 4; j++)
                    acc[i][j] = MFMA16(a2[ks][i], b2[ks][j], acc[i][j]);

        if (nxt) stage_write(cur ^ 1);         // cvt + LDS write, other buffer
        cur ^= 1;
    }
    __syncthreads();   // all LDS reads done before V-path smem reuse

    if (wsel < 2) {
        // Q (pre-scaled) / K: [bh][s][dk]
        __bf16* Out = wsel ? Kb : Qb;
        const float sc = wsel ? 1.f : Q_SCALE;
#pragma unroll
        for (int i = 0; i < 4; i++) {
#pragma unroll
            for (int r = 0; r < 4; r++) {
                const int R  = row0 + wrow * 64 + i * 16 + quad * 4 + r;
                const int bb = R >> 11;
                const int s  = R & (SEQ - 1);
#pragma unroll
                for (int j = 0; j < 4; j++) {
                    const int e  = lcol0 + wcol * 64 + j * 16 + m;
                    const int h  = e >> 6;
                    const int dk = e & (D_K - 1);
                    Out[((size_t)(bb * NUM_HEADS + h) * SEQ + s) * D_K + dk] =
                        (__bf16)(acc[i][j][r] * sc);
                }
            }
        }
    } else {
        // V: transpose tile through LDS, store coalesced V^T rows.
        __bf16* Ls = (__bf16*)smem;   // [128][136]
#pragma unroll
        for (int i = 0; i < 4; i++)
#pragma unroll
            for (int r = 0; r < 4; r++)
#pragma unroll
                for (int j = 0; j < 4; j++)
                    Ls[(wcol * 64 + j * 16 + m) * 136 +
                       wrow * 64 + i * 16 + quad * 4 + r] = (__bf16)acc[i][j][r];
        __syncthreads();
        const int bb   = row0 >> 11;
        const int sloc = row0 & (SEQ - 1);
#pragma unroll
        for (int i = 0; i < 8; i++) {
            const int c   = i * 256 + threadIdx.x;
            const int dkl = c >> 4;
            const int sc  = c & 15;
            const bf16x8 v = load8(Ls + dkl * 136 + sc * 8);
            const int e  = lcol0 + dkl;
            const int h  = e >> 6;
            const int dk = e & (D_K - 1);
            const int bh = bb * NUM_HEADS + h;
            *reinterpret_cast<bf16x8*>(
                Vtg + ((size_t)bh * D_K + dk) * SEQ + sloc + sc * 8) = v;
        }
    }
}

// ---------------------------------------------------------------------------
// Flash attention, causal, ONE STRIP PER BLOCK + DOUBLE-BUFFERED LDS staging.
// R19: restored to the best measured per-dispatch variant (R16: s = 31-y,
// no setprio, 44.3 us). R18's zero-LDS direct-global version was 2.8x slower
// (latency-bound scattered VMEM) -- LDS staging is load-bearing here.
// QBLK=64, grid (32 bh, 32 strips), 1024 blocks = 4/CU, big strips first.
// Register-resident P (zip-permlane), ones-MFMA row sums.
// ---------------------------------------------------------------------------
__global__ __launch_bounds__(256) void attn_kernel(
    const __bf16* __restrict__ Qb,
    const __bf16* __restrict__ Kb,
    const __bf16* __restrict__ Vtg,
    __bf16* __restrict__ Cc)
{
    __shared__ alignas(16) __bf16 Ks[2][64 * 64];  // ping-pong, 16 KB
    __shared__ alignas(16) __bf16 Vt[2][64 * 64];  // ping-pong, 16 KB

    const int lane = threadIdx.x & 63;
    const int wid  = threadIdx.x >> 6;
    const int m    = lane & 15;
    const int quad = lane >> 4;
    const int bh   = blockIdx.x;
    const int b    = bh >> 4;
    const int h    = bh & (NUM_HEADS - 1);
    const int s    = 31 - blockIdx.y;              // strip index, big first

    const __bf16* Qp = Qb  + (size_t)bh * SEQ * D_K;
    const __bf16* Kp = Kb  + (size_t)bh * SEQ * D_K;
    const __bf16* Vp = Vtg + (size_t)bh * D_K * SEQ;

    // staging lambda: 64x64 K tile + 64x64 V^T tile into buffer `buf`
    auto stage = [&](int k0, int buf) {
#pragma unroll
        for (int i = 0; i < 2; i++) {
            const int slot = wid * 128 + i * 64 + lane;
            const int row  = slot >> 3;
            const int cg   = (slot & 7) ^ (row & 7);
            gload16(Kp + (size_t)(k0 + row) * D_K + cg * 8,
                    (const char*)&Ks[buf][0] + (size_t)(wid * 128 + i * 64) * 16);
            gload16(Vp + (size_t)row * SEQ + k0 + cg * 8,
                    (const char*)&Vt[buf][0] + (size_t)(wid * 128 + i * 64) * 16);
        }
    };

    bf16x8 vone;
#pragma unroll
    for (int e = 0; e < 8; e++) vone[e] = (__bf16)1.0f;

    const int q0 = s * 64 + wid * 16;              // this wave's 16 q rows

    const bf16x8 qB0 = load8(Qp + (size_t)(q0 + m) * D_K + quad * 8);
    const bf16x8 qB1 = load8(Qp + (size_t)(q0 + m) * D_K + 32 + quad * 8);

    f32x4 oacc[4];
#pragma unroll
    for (int c = 0; c < 4; c++) oacc[c] = (f32x4){0.f, 0.f, 0.f, 0.f};
    f32x4 accL = (f32x4){0.f, 0.f, 0.f, 0.f};      // l for q = q0+quad*4+r

    stage(0, 0);
    int cur = 0;
#pragma unroll 1
    for (int t = 0; t <= s; t++) {
        __syncthreads();             // tile t's staging complete
        if (t < s) stage((t + 1) * 64, cur ^ 1);   // prefetch: in flight
                                                   // through compute below
        const bool diag = (t == s);
        const int  k0   = t * 64;
        const __bf16* Kc = &Ks[cur][0];
        const __bf16* Vc = &Vt[cur][0];

        // ---- S^T = K Q^T (rows=keys, cols=q); exp2; pack to bf16 words.
        // Lane (m,quad) produces keys {kb*16+quad*4 .. +3} for q=q0+m:
        // w0[kb] = keys {4*quad, 4*quad+1}, w1[kb] = {4*quad+2, 4*quad+3}.
        uint32_t w0[4], w1[4];
#pragma unroll
        for (int kb = 0; kb < 4; kb++) {
            const int rK = kb * 16 + m;
            const bf16x8 kfA = load8(Kc + rK * 64 + ((quad ^ (rK & 7)) * 8));
            const bf16x8 kfB = load8(Kc + rK * 64 + (((quad + 4) ^ (rK & 7)) * 8));
            f32x4 st = (f32x4){0.f, 0.f, 0.f, 0.f};
            st = MFMA16(kfA, qB0, st);
            st = MFMA16(kfB, qB1, st);
            const int q    = q0 + m;
            const int keyb = k0 + kb * 16 + quad * 4;
            float ex[4];
#pragma unroll
            for (int r = 0; r < 4; r++) {
                float e = __builtin_amdgcn_exp2f(st[r]);
                if (diag) e = (keyb + r <= q) ? e : 0.f;
                ex[r] = e;
            }
            w0[kb] = cvtpk(ex[0], ex[1]);
            w1[kb] = cvtpk(ex[2], ex[3]);
        }

        // ---- redistribute to A-fragments (keys 8*quad..+7 per lane).
        // Zip semantics, verified key-by-key:
        //   (X=w[lo], Y=w[hi]); swap32; swap16 => X=word j, Y=word j+2.
        uint32_t pa0 = w0[0], pa2 = w0[1]; swap32(pa0, pa2); swap16(pa0, pa2);
        uint32_t pa1 = w1[0], pa3 = w1[1]; swap32(pa1, pa3); swap16(pa1, pa3);
        uint32_t pb0 = w0[2], pb2 = w0[3]; swap32(pb0, pb2); swap16(pb0, pb2);
        uint32_t pb1 = w1[2], pb3 = w1[3]; swap32(pb1, pb3); swap16(pb1, pb3);
        const u32x4 ua = (u32x4){pa0, pa1, pa2, pa3};
        const u32x4 ub = (u32x4){pb0, pb1, pb2, pb3};
        const bf16x8 pfA = __builtin_bit_cast(bf16x8, ua);
        const bf16x8 pfB = __builtin_bit_cast(bf16x8, ub);

        // ---- row-sum via ones-MFMA: accL[r] = sum_k P[q=quad*4+r][k]
        accL = MFMA16(pfA, vone, accL);
        accL = MFMA16(pfB, vone, accL);

        // ---- P.V ----
#pragma unroll
        for (int c = 0; c < 4; c++) {
            const int rV = c * 16 + m;
            const bf16x8 vfA = load8(Vc + rV * 64 + ((quad ^ (rV & 7)) * 8));
            const bf16x8 vfB = load8(Vc + rV * 64 + (((quad + 4) ^ (rV & 7)) * 8));
            oacc[c] = MFMA16(pfA, vfA, oacc[c]);
            oacc[c] = MFMA16(pfB, vfB, oacc[c]);
        }
        cur ^= 1;
    }

    // ---- epilogue: l is already per-register in accL ----
#pragma unroll
    for (int r = 0; r < 4; r++) {
        const float inv = 1.f / accL[r];
        const int srow = q0 + quad * 4 + r;
#pragma unroll
        for (int c = 0; c < 4; c++) {
            const size_t o2 = ((size_t)(b * SEQ + srow)) * D_MODEL + h * D_K + c * 16 + m;
            Cc[o2] = (__bf16)(oacc[c][r] * inv);
        }
    }
}

// ---------------------------------------------------------------------------
// Output projection, R19: Out = Cc * Wo^T + bo with Wo read DIRECTLY as fp32
// (reg-staged convert-on-the-fly, same T14 split as qkv); Cc (bf16) keeps the
// async gload16 path. 64x64 tile, grid (64,16) = 1024 blocks = 4/CU, one
// barrier per K-step.
// ---------------------------------------------------------------------------
__global__ __launch_bounds__(256) void oproj_kernel(
    const __bf16* __restrict__ Cc,
    const float* __restrict__ Wof,
    const float* __restrict__ bo,
    float* __restrict__ Out)
{
    __shared__ alignas(16) __bf16 As[2][64 * 64];  // ping-pong, 8 KB each
    __shared__ alignas(16) __bf16 Bs[2][64 * 64];  // ping-pong, 8 KB each

    const int lane = threadIdx.x & 63;
    const int wid  = threadIdx.x >> 6;
    const int m    = lane & 15;
    const int quad = lane >> 4;
    const int wrow = wid >> 1, wcol = wid & 1;
    const int row0 = blockIdx.x * 64;
    const int col0 = blockIdx.y * 64;

    f32x4 rbw[2][2];   // staged fp32 Wo registers for one K-step

    auto stageA = [&](int k0, int buf) {
#pragma unroll
        for (int i = 0; i < 2; i++) {
            const int slot = wid * 128 + i * 64 + lane;
            const int row  = slot >> 3;
            const int cg   = (slot & 7) ^ (row & 7);
            gload16(Cc + (size_t)(row0 + row) * D_MODEL + k0 + cg * 8,
                    (const char*)&As[buf][0] + (size_t)slot * 16);
        }
    };
    auto loadB = [&](int k0) {
#pragma unroll
        for (int i = 0; i < 2; i++) {
            const int slot = wid * 128 + i * 64 + lane;
            const int row  = slot >> 3;
            const int cg   = (slot & 7) ^ (row & 7);
            const float* p = Wof + (size_t)(col0 + row) * D_MODEL + k0 + cg * 8;
            rbw[i][0] = *reinterpret_cast<const f32x4*>(p);
            rbw[i][1] = *reinterpret_cast<const f32x4*>(p + 4);
        }
    };
    auto writeB = [&](int buf) {
#pragma unroll
        for (int i = 0; i < 2; i++) {
            const int slot = wid * 128 + i * 64 + lane;
            bf16x8 v;
#pragma unroll
            for (int e = 0; e < 4; e++) {
                v[e] = (__bf16)rbw[i][0][e]; v[4 + e] = (__bf16)rbw[i][1][e];
            }
            *reinterpret_cast<bf16x8*>((char*)&Bs[buf][0] + (size_t)slot * 16) = v;
        }
    };

    f32x4 acc[2][2];
#pragma unroll
    for (int i = 0; i < 2; i++)
#pragma unroll
        for (int j = 0; j < 2; j++) acc[i][j] = (f32x4){0.f, 0.f, 0.f, 0.f};

    stageA(0, 0);
    loadB(0);
    writeB(0);
    int cur = 0;
#pragma unroll 1
    for (int k0 = 0; k0 < D_MODEL; k0 += 64) {
        __syncthreads();                       // buffer `cur` ready
        const bool nxt = (k0 + 64 < D_MODEL);
        if (nxt) { stageA(k0 + 64, cur ^ 1); loadB(k0 + 64); }

        bf16x8 a2[2][2], b2[2][2];
#pragma unroll
        for (int ks = 0; ks < 2; ks++) {
#pragma unroll
            for (int i = 0; i < 2; i++) {
                const int rA = wrow * 32 + i * 16 + m;
                a2[ks][i] = load8(&As[cur][0] + rA * 64 + (((ks * 4 + quad) ^ (rA & 7)) * 8));
                const int rB = wcol * 32 + i * 16 + m;
                b2[ks][i] = load8(&Bs[cur][0] + rB * 64 + (((ks * 4 + quad) ^ (rB & 7)) * 8));
            }
        }
#pragma unroll
        for (int ks = 0; ks < 2; ks++)
#pragma unroll
            for (int i = 0; i < 2; i++)
#pragma unroll
                for (int j = 0; j < 2; j++)
                    acc[i][j] = MFMA16(a2[ks][i], b2[ks][j], acc[i][j]);

        if (nxt) writeB(cur ^ 1);
        cur ^= 1;
    }

#pragma unroll
    for (int i = 0; i < 2; i++) {
#pragma unroll
        for (int r = 0; r < 4; r++) {
            const int R = row0 + wrow * 32 + i * 16 + quad * 4 + r;
#pragma unroll
            for (int j = 0; j < 2; j++) {
                const int E = col0 + wcol * 32 + j * 16 + m;
                Out[(size_t)R * D_MODEL + E] = acc[i][j][r] + bo[E];
            }
        }
    }
}

// ---------------------------------------------------------------------------
extern "C" void kernel_launch(void* const* d_in, const int* in_sizes, int n_in,
                              void* d_out, int out_size, void* d_ws, size_t ws_size,
                              hipStream_t stream) {
    const float* x  = (const float*)d_in[0];
    const float* Wq = (const float*)d_in[1];
    const float* Wk = (const float*)d_in[2];
    const float* Wv = (const float*)d_in[3];
    const float* Wo = (const float*)d_in[4];
    const float* bo = (const float*)d_in[5];
    // d_in[6] = causal mask — recomputed from indices, not read.

    const size_t elems = (size_t)M_TOTAL * D_MODEL;    // 4194304
    __bf16* Cc  = (__bf16*)d_ws;       // 8 MB
    __bf16* Qb  = Cc + elems;
    __bf16* Kb  = Qb + elems;
    __bf16* Vtg = Kb + elems;          // [32][64][2048]  (V^T); end: 32 MB

    // 1) QKV projections from fp32 sources (convert fused into staging)
    qkv_kernel<<<dim3(M_TOTAL / 128, 3 * D_MODEL / 128), 256, 0, stream>>>(
        x, Wq, Wk, Wv, Qb, Kb, Vtg);

    // 2) causal flash attention: one strip per block, big-first, 4 blocks/CU
    attn_kernel<<<dim3(BATCH * NUM_HEADS, 32), 256, 0, stream>>>(
        Qb, Kb, Vtg, Cc);

    // 3) output projection + bias -> fp32 out (Wo converted in staging)
    oproj_kernel<<<dim3(M_TOTAL / 64, D_MODEL / 64), 256, 0, stream>>>(
        Cc, Wo, bo, (float*)d_out);
}

// Round 10
// 215.894 us; speedup vs baseline: 1.2034x; 1.0537x over previous
//
#include <hip/hip_runtime.h>
#include <hip/hip_bf16.h>
#include <stdint.h>

typedef __bf16 bf16x8 __attribute__((ext_vector_type(8)));
typedef __bf16 bf16x4 __attribute__((ext_vector_type(4)));
typedef float  f32x4  __attribute__((ext_vector_type(4)));
typedef unsigned int u32x4 __attribute__((ext_vector_type(4)));

#define D_MODEL 1024
#define NUM_HEADS 16
#define D_K 64
#define BATCH 2
#define SEQ 2048
#define M_TOTAL (BATCH * SEQ)   // 4096

// 0.125 (1/sqrt(64)) * log2(e): folded into Q at the qkv epilogue so the
// attention softmax is a bare exp2 (v_exp_f32), no per-element scale mul.
#define Q_SCALE 0.18033688011112042f

static __device__ __forceinline__ bf16x8 load8(const __bf16* p) {
    return *reinterpret_cast<const bf16x8*>(p);
}

#define MFMA16(a, b, c) __builtin_amdgcn_mfma_f32_16x16x32_bf16((a), (b), (c), 0, 0, 0)

// Async global->LDS, 16B per lane. LDS dest = wave-uniform base + lane*16.
static __device__ __forceinline__ void gload16(const void* g, const void* lds) {
    __builtin_amdgcn_global_load_lds(
        (const __attribute__((address_space(1))) uint32_t*)g,
        (__attribute__((address_space(3))) uint32_t*)lds,
        16, 0, 0);
}

// Pack two f32 -> one u32 of 2 bf16 (lo = first arg). No builtin on gfx950.
static __device__ __forceinline__ uint32_t cvtpk(float lo, float hi) {
    uint32_t r;
    asm("v_cvt_pk_bf16_f32 %0, %1, %2" : "=v"(r) : "v"(lo), "v"(hi));
    return r;
}
// CDNA4 zip semantics ("DST rows 2:3 <-> SRC rows 0:1", rows = 16 lanes):
//   swap32: a' = (a@q0, a@q1, b@q0, b@q1), b' = (a@q2, a@q3, b@q2, b@q3)
static __device__ __forceinline__ void swap32(uint32_t& a, uint32_t& b) {
    asm("v_permlane32_swap_b32 %0, %1" : "+v"(a), "+v"(b));
}
// swap16 ("DST odd rows <-> SRC even rows"):
//   a' = (a@q0, b@q0, a@q2, b@q2), b' = (a@q1, b@q1, a@q3, b@q3)
static __device__ __forceinline__ void swap16(uint32_t& a, uint32_t& b) {
    asm("v_permlane16_swap_b32 %0, %1" : "+v"(a), "+v"(b));
}

// ---------------------------------------------------------------------------
// One launch: x (2048 blocks) + 4 weight matrices (512 blocks each) fp32->bf16.
// R20: restored (R19's fusion doubled qkv's HBM fetch: fp32 X/W re-read by
// 24/32 blocks each -> convert-once in bf16 is structurally right).
// ---------------------------------------------------------------------------
__global__ __launch_bounds__(256) void convert_all(
    const float* __restrict__ X,
    const float* __restrict__ Wq, const float* __restrict__ Wk,
    const float* __restrict__ Wv, const float* __restrict__ Wo,
    __bf16* __restrict__ xb,
    __bf16* __restrict__ dq, __bf16* __restrict__ dk,
    __bf16* __restrict__ dv, __bf16* __restrict__ dw)
{
    const float* src; __bf16* dst; size_t idx;
    if (blockIdx.x < 2048) {
        src = X; dst = xb;
        idx = (size_t)blockIdx.x * 256 + threadIdx.x;
    } else {
        const int wb  = blockIdx.x - 2048;
        const int sel = wb >> 9;
        src = (sel == 0) ? Wq : (sel == 1) ? Wk : (sel == 2) ? Wv : Wo;
        dst = (sel == 0) ? dq : (sel == 1) ? dk : (sel == 2) ? dv : dw;
        idx = (size_t)(wb & 511) * 256 + threadIdx.x;
    }
    const f32x4 a = *reinterpret_cast<const f32x4*>(src + idx * 8);
    const f32x4 b = *reinterpret_cast<const f32x4*>(src + idx * 8 + 4);
    bf16x8 r;
#pragma unroll
    for (int e = 0; e < 4; e++) { r[e] = (__bf16)a[e]; r[4 + e] = (__bf16)b[e]; }
    *reinterpret_cast<bf16x8*>(dst + idx * 8) = r;
}

// ---------------------------------------------------------------------------
// QKV GEMM (R16 config, restored): 128x128 tile, BK=64, swizzled gload16
// staging, double-buffered prefetch loop (one barrier per K-step, next
// tile's loads in flight through compute). LDS 64 KB -> 2 blocks/CU.
// Q output pre-scaled by Q_SCALE. V transposed through LDS -> V^T.
// grid = (32, 24), block = 256.
// ---------------------------------------------------------------------------
__global__ __launch_bounds__(256) void qkv_kernel(
    const __bf16* __restrict__ Xb,
    const __bf16* __restrict__ Wqb,
    const __bf16* __restrict__ Wkb,
    const __bf16* __restrict__ Wvb,
    __bf16* __restrict__ Qb,
    __bf16* __restrict__ Kb,
    __bf16* __restrict__ Vtg)
{
    __shared__ alignas(16) char smem[65536];   // A[2]16K + B[2]16K; V scratch 34K
    __bf16* As0 = (__bf16*)smem;               // [2][128*64], chunk-swizzled
    __bf16* Bs0 = As0 + 2 * 128 * 64;

    const int lane = threadIdx.x & 63;
    const int wid  = threadIdx.x >> 6;
    const int m    = lane & 15;
    const int quad = lane >> 4;
    const int wrow = wid >> 1, wcol = wid & 1;
    const int row0 = blockIdx.x * 128;
    const int col0 = blockIdx.y * 128;
    const int wsel = col0 >> 10;
    const int lcol0 = col0 & 1023;

    const __bf16* W = (wsel == 0) ? Wqb : (wsel == 1) ? Wkb : Wvb;

    // staging: 128x64 A-tile + 128x64 B-tile into buffer `buf`
    auto stage = [&](int k0, int buf) {
#pragma unroll
        for (int i = 0; i < 4; i++) {
            const int slot = wid * 256 + i * 64 + lane;
            const int row  = slot >> 3;
            const int cg   = (slot & 7) ^ (row & 7);
            gload16(Xb + (size_t)(row0 + row) * D_MODEL + k0 + cg * 8,
                    (const char*)(As0 + buf * 8192) + (size_t)(wid * 256 + i * 64) * 16);
            gload16(W + (size_t)(lcol0 + row) * D_MODEL + k0 + cg * 8,
                    (const char*)(Bs0 + buf * 8192) + (size_t)(wid * 256 + i * 64) * 16);
        }
    };

    f32x4 acc[4][4];
#pragma unroll
    for (int i = 0; i < 4; i++)
#pragma unroll
        for (int j = 0; j < 4; j++) acc[i][j] = (f32x4){0.f, 0.f, 0.f, 0.f};

    stage(0, 0);
    int cur = 0;
#pragma unroll 1
    for (int k0 = 0; k0 < D_MODEL; k0 += 64) {
        __syncthreads();                       // buffer `cur` staged
        if (k0 + 64 < D_MODEL) stage(k0 + 64, cur ^ 1);   // in flight through
                                                          // compute below
        const __bf16* As = As0 + cur * 8192;
        const __bf16* Bs = Bs0 + cur * 8192;

        bf16x8 a2[2][4], b2[2][4];
#pragma unroll
        for (int ks = 0; ks < 2; ks++) {
#pragma unroll
            for (int i = 0; i < 4; i++) {
                const int rA = wrow * 64 + i * 16 + m;
                a2[ks][i] = load8(As + rA * 64 + (((ks * 4 + quad) ^ (rA & 7)) * 8));
                const int rB = wcol * 64 + i * 16 + m;
                b2[ks][i] = load8(Bs + rB * 64 + (((ks * 4 + quad) ^ (rB & 7)) * 8));
            }
        }
#pragma unroll
        for (int ks = 0; ks < 2; ks++)
#pragma unroll
            for (int i = 0; i < 4; i++)
#pragma unroll
                for (int j = 0; j < 4; j++)
                    acc[i][j] = MFMA16(a2[ks][i], b2[ks][j], acc[i][j]);
        cur ^= 1;
    }
    __syncthreads();   // all LDS reads done before V-path smem reuse

    if (wsel < 2) {
        // Q (pre-scaled) / K: [bh][s][dk]
        __bf16* Out = wsel ? Kb : Qb;
        const float sc = wsel ? 1.f : Q_SCALE;
#pragma unroll
        for (int i = 0; i < 4; i++) {
#pragma unroll
            for (int r = 0; r < 4; r++) {
                const int R  = row0 + wrow * 64 + i * 16 + quad * 4 + r;
                const int bb = R >> 11;
                const int s  = R & (SEQ - 1);
#pragma unroll
                for (int j = 0; j < 4; j++) {
                    const int e  = lcol0 + wcol * 64 + j * 16 + m;
                    const int h  = e >> 6;
                    const int dk = e & (D_K - 1);
                    Out[((size_t)(bb * NUM_HEADS + h) * SEQ + s) * D_K + dk] =
                        (__bf16)(acc[i][j][r] * sc);
                }
            }
        }
    } else {
        // V: transpose tile through LDS, store coalesced V^T rows.
        __bf16* Ls = (__bf16*)smem;   // [128][136]
#pragma unroll
        for (int i = 0; i < 4; i++)
#pragma unroll
            for (int r = 0; r < 4; r++)
#pragma unroll
                for (int j = 0; j < 4; j++)
                    Ls[(wcol * 64 + j * 16 + m) * 136 +
                       wrow * 64 + i * 16 + quad * 4 + r] = (__bf16)acc[i][j][r];
        __syncthreads();
        const int bb   = row0 >> 11;
        const int sloc = row0 & (SEQ - 1);
#pragma unroll
        for (int i = 0; i < 8; i++) {
            const int c   = i * 256 + threadIdx.x;
            const int dkl = c >> 4;
            const int sc  = c & 15;
            const bf16x8 v = load8(Ls + dkl * 136 + sc * 8);
            const int e  = lcol0 + dkl;
            const int h  = e >> 6;
            const int dk = e & (D_K - 1);
            const int bh = bb * NUM_HEADS + h;
            *reinterpret_cast<bf16x8*>(
                Vtg + ((size_t)bh * D_K + dk) * SEQ + sloc + sc * 8) = v;
        }
    }
}

// ---------------------------------------------------------------------------
// Flash attention, causal. R20: K staged in LDS (proven prefetch-barrier
// pipeline, R16) + V read DIRECTLY from global -- the half of R18 the
// evidence supports. R18's 128-us failure was the K-fragment->MFMA serial
// chain (4 dependent load->MFMA steps/tile); V's 8 loads are independent,
// issued at tile-top, consumed ~400 cyc later after QK+exp+permlane (T14;
// m169: drop V-staging when K/V L2-fit, keep K staged -> +26%). Addressing
// HW-verified by R18 (passed numerically). Staging gloads per tile halve,
// V's LDS write+read round-trip disappears, LDS 32 -> 16 KB.
// QBLK=64, grid (32 bh, 32 strips), 1024 blocks = 4/CU, big strips first.
// Register-resident P (zip-permlane), ones-MFMA row sums.
// ---------------------------------------------------------------------------
__global__ __launch_bounds__(256) void attn_kernel(
    const __bf16* __restrict__ Qb,
    const __bf16* __restrict__ Kb,
    const __bf16* __restrict__ Vtg,
    __bf16* __restrict__ Cc)
{
    __shared__ alignas(16) __bf16 Ks[2][64 * 64];  // ping-pong, 16 KB total

    const int lane = threadIdx.x & 63;
    const int wid  = threadIdx.x >> 6;
    const int m    = lane & 15;
    const int quad = lane >> 4;
    const int bh   = blockIdx.x;
    const int b    = bh >> 4;
    const int h    = bh & (NUM_HEADS - 1);
    const int s    = 31 - blockIdx.y;              // strip index, big first

    const __bf16* Qp = Qb  + (size_t)bh * SEQ * D_K;
    const __bf16* Kp = Kb  + (size_t)bh * SEQ * D_K;
    const __bf16* Vp = Vtg + (size_t)bh * D_K * SEQ;

    // staging lambda: 64x64 K tile into buffer `buf` (V is not staged)
    auto stage = [&](int k0, int buf) {
#pragma unroll
        for (int i = 0; i < 2; i++) {
            const int slot = wid * 128 + i * 64 + lane;
            const int row  = slot >> 3;
            const int cg   = (slot & 7) ^ (row & 7);
            gload16(Kp + (size_t)(k0 + row) * D_K + cg * 8,
                    (const char*)&Ks[buf][0] + (size_t)(wid * 128 + i * 64) * 16);
        }
    };

    bf16x8 vone;
#pragma unroll
    for (int e = 0; e < 8; e++) vone[e] = (__bf16)1.0f;

    const int q0 = s * 64 + wid * 16;              // this wave's 16 q rows

    const bf16x8 qB0 = load8(Qp + (size_t)(q0 + m) * D_K + quad * 8);
    const bf16x8 qB1 = load8(Qp + (size_t)(q0 + m) * D_K + 32 + quad * 8);

    f32x4 oacc[4];
#pragma unroll
    for (int c = 0; c < 4; c++) oacc[c] = (f32x4){0.f, 0.f, 0.f, 0.f};
    f32x4 accL = (f32x4){0.f, 0.f, 0.f, 0.f};      // l for q = q0+quad*4+r

    stage(0, 0);
    int cur = 0;
#pragma unroll 1
    for (int t = 0; t <= s; t++) {
        __syncthreads();             // tile t's K staging complete
        if (t < s) stage((t + 1) * 64, cur ^ 1);   // K prefetch: in flight
                                                   // through compute below
        const bool diag = (t == s);
        const int  k0   = t * 64;
        const __bf16* Kc = &Ks[cur][0];

        // ---- V fragments direct from global: 8 independent 16B loads,
        // issued now, consumed after QK+exp+permlane (latency hidden).
        // vfA[c] = V^T[c*16+m][k0 + quad*8 ..], vfB at +32 (R18-verified).
        bf16x8 vfA[4], vfB[4];
#pragma unroll
        for (int c = 0; c < 4; c++) {
            const int rV = c * 16 + m;
            vfA[c] = load8(Vp + (size_t)rV * SEQ + k0 + quad * 8);
            vfB[c] = load8(Vp + (size_t)rV * SEQ + k0 + 32 + quad * 8);
        }

        // ---- S^T = K Q^T (rows=keys, cols=q); exp2; pack to bf16 words.
        // Lane (m,quad) produces keys {kb*16+quad*4 .. +3} for q=q0+m:
        // w0[kb] = keys {4*quad, 4*quad+1}, w1[kb] = {4*quad+2, 4*quad+3}.
        uint32_t w0[4], w1[4];
#pragma unroll
        for (int kb = 0; kb < 4; kb++) {
            const int rK = kb * 16 + m;
            const bf16x8 kfA = load8(Kc + rK * 64 + ((quad ^ (rK & 7)) * 8));
            const bf16x8 kfB = load8(Kc + rK * 64 + (((quad + 4) ^ (rK & 7)) * 8));
            f32x4 st = (f32x4){0.f, 0.f, 0.f, 0.f};
            st = MFMA16(kfA, qB0, st);
            st = MFMA16(kfB, qB1, st);
            const int q    = q0 + m;
            const int keyb = k0 + kb * 16 + quad * 4;
            float ex[4];
#pragma unroll
            for (int r = 0; r < 4; r++) {
                float e = __builtin_amdgcn_exp2f(st[r]);
                if (diag) e = (keyb + r <= q) ? e : 0.f;
                ex[r] = e;
            }
            w0[kb] = cvtpk(ex[0], ex[1]);
            w1[kb] = cvtpk(ex[2], ex[3]);
        }

        // ---- redistribute to A-fragments (keys 8*quad..+7 per lane).
        // Zip semantics, verified key-by-key:
        //   (X=w[lo], Y=w[hi]); swap32; swap16 => X=word j, Y=word j+2.
        uint32_t pa0 = w0[0], pa2 = w0[1]; swap32(pa0, pa2); swap16(pa0, pa2);
        uint32_t pa1 = w1[0], pa3 = w1[1]; swap32(pa1, pa3); swap16(pa1, pa3);
        uint32_t pb0 = w0[2], pb2 = w0[3]; swap32(pb0, pb2); swap16(pb0, pb2);
        uint32_t pb1 = w1[2], pb3 = w1[3]; swap32(pb1, pb3); swap16(pb1, pb3);
        const u32x4 ua = (u32x4){pa0, pa1, pa2, pa3};
        const u32x4 ub = (u32x4){pb0, pb1, pb2, pb3};
        const bf16x8 pfA = __builtin_bit_cast(bf16x8, ua);
        const bf16x8 pfB = __builtin_bit_cast(bf16x8, ub);

        // ---- row-sum via ones-MFMA: accL[r] = sum_k P[q=quad*4+r][k]
        accL = MFMA16(pfA, vone, accL);
        accL = MFMA16(pfB, vone, accL);

        // ---- P.V (V already in registers) ----
#pragma unroll
        for (int c = 0; c < 4; c++) {
            oacc[c] = MFMA16(pfA, vfA[c], oacc[c]);
            oacc[c] = MFMA16(pfB, vfB[c], oacc[c]);
        }
        cur ^= 1;
    }

    // ---- epilogue: l is already per-register in accL ----
#pragma unroll
    for (int r = 0; r < 4; r++) {
        const float inv = 1.f / accL[r];
        const int srow = q0 + quad * 4 + r;
#pragma unroll
        for (int c = 0; c < 4; c++) {
            const size_t o2 = ((size_t)(b * SEQ + srow)) * D_MODEL + h * D_K + c * 16 + m;
            Cc[o2] = (__bf16)(oacc[c][r] * inv);
        }
    }
}

// ---------------------------------------------------------------------------
// Output projection (R16 config, restored): Out = Cc * Wo^T + bo (fp32).
// 64x64 tile, grid (64,16) = 1024 blocks = 4/CU, double-buffered prefetch
// loop (one barrier per K-step), both operands via gload16 (bf16).
// ---------------------------------------------------------------------------
__global__ __launch_bounds__(256) void oproj_kernel(
    const __bf16* __restrict__ Cc,
    const __bf16* __restrict__ Wob,
    const float* __restrict__ bo,
    float* __restrict__ Out)
{
    __shared__ alignas(16) __bf16 As[2][64 * 64];  // ping-pong, 8 KB each
    __shared__ alignas(16) __bf16 Bs[2][64 * 64];  // ping-pong, 8 KB each

    const int lane = threadIdx.x & 63;
    const int wid  = threadIdx.x >> 6;
    const int m    = lane & 15;
    const int quad = lane >> 4;
    const int wrow = wid >> 1, wcol = wid & 1;
    const int row0 = blockIdx.x * 64;
    const int col0 = blockIdx.y * 64;

    auto stage = [&](int k0, int buf) {
#pragma unroll
        for (int i = 0; i < 2; i++) {
            const int slot = wid * 128 + i * 64 + lane;
            const int row  = slot >> 3;
            const int cg   = (slot & 7) ^ (row & 7);
            gload16(Cc + (size_t)(row0 + row) * D_MODEL + k0 + cg * 8,
                    (const char*)&As[buf][0] + (size_t)slot * 16);
            gload16(Wob + (size_t)(col0 + row) * D_MODEL + k0 + cg * 8,
                    (const char*)&Bs[buf][0] + (size_t)slot * 16);
        }
    };

    f32x4 acc[2][2];
#pragma unroll
    for (int i = 0; i < 2; i++)
#pragma unroll
        for (int j = 0; j < 2; j++) acc[i][j] = (f32x4){0.f, 0.f, 0.f, 0.f};

    stage(0, 0);
    int cur = 0;
#pragma unroll 1
    for (int k0 = 0; k0 < D_MODEL; k0 += 64) {
        __syncthreads();                       // buffer `cur` staged
        if (k0 + 64 < D_MODEL) stage(k0 + 64, cur ^ 1);

        bf16x8 a2[2][2], b2[2][2];
#pragma unroll
        for (int ks = 0; ks < 2; ks++) {
#pragma unroll
            for (int i = 0; i < 2; i++) {
                const int rA = wrow * 32 + i * 16 + m;
                a2[ks][i] = load8(&As[cur][0] + rA * 64 + (((ks * 4 + quad) ^ (rA & 7)) * 8));
                const int rB = wcol * 32 + i * 16 + m;
                b2[ks][i] = load8(&Bs[cur][0] + rB * 64 + (((ks * 4 + quad) ^ (rB & 7)) * 8));
            }
        }
#pragma unroll
        for (int ks = 0; ks < 2; ks++)
#pragma unroll
            for (int i = 0; i < 2; i++)
#pragma unroll
                for (int j = 0; j < 2; j++)
                    acc[i][j] = MFMA16(a2[ks][i], b2[ks][j], acc[i][j]);
        cur ^= 1;
    }

#pragma unroll
    for (int i = 0; i < 2; i++) {
#pragma unroll
        for (int r = 0; r < 4; r++) {
            const int R = row0 + wrow * 32 + i * 16 + quad * 4 + r;
#pragma unroll
            for (int j = 0; j < 2; j++) {
                const int E = col0 + wcol * 32 + j * 16 + m;
                Out[(size_t)R * D_MODEL + E] = acc[i][j][r] + bo[E];
            }
        }
    }
}

// ---------------------------------------------------------------------------
extern "C" void kernel_launch(void* const* d_in, const int* in_sizes, int n_in,
                              void* d_out, int out_size, void* d_ws, size_t ws_size,
                              hipStream_t stream) {
    const float* x  = (const float*)d_in[0];
    const float* Wq = (const float*)d_in[1];
    const float* Wk = (const float*)d_in[2];
    const float* Wv = (const float*)d_in[3];
    const float* Wo = (const float*)d_in[4];
    const float* bo = (const float*)d_in[5];
    // d_in[6] = causal mask — recomputed from indices, not read.

    const size_t elems  = (size_t)M_TOTAL * D_MODEL;   // 4194304
    const size_t welems = (size_t)D_MODEL * D_MODEL;   // 1048576
    __bf16* xb  = (__bf16*)d_ws;       // seg0: x (bf16) -> later Cc (aliased)
    __bf16* Qb  = xb + elems;
    __bf16* Kb  = Qb + elems;
    __bf16* Vtg = Kb + elems;          // [32][64][2048]  (V^T)
    __bf16* Wqb = Vtg + elems;
    __bf16* Wkb = Wqb + welems;
    __bf16* Wvb = Wkb + welems;
    __bf16* Wob = Wvb + welems;        // end: 40 MB
    __bf16* Cc  = xb;

    // 0) all fp32 -> bf16 conversions in one launch
    convert_all<<<dim3(4096), 256, 0, stream>>>(
        x, Wq, Wk, Wv, Wo, xb, Wqb, Wkb, Wvb, Wob);

    // 1) QKV projections (Q pre-scaled by 0.125*log2e), dbuf prefetch loop
    qkv_kernel<<<dim3(M_TOTAL / 128, 3 * D_MODEL / 128), 256, 0, stream>>>(
        xb, Wqb, Wkb, Wvb, Qb, Kb, Vtg);

    // 2) causal flash attention: K staged + V direct-from-global
    attn_kernel<<<dim3(BATCH * NUM_HEADS, 32), 256, 0, stream>>>(
        Qb, Kb, Vtg, Cc);

    // 3) output projection + bias -> fp32 out (64x64 tiles, dbuf prefetch)
    oproj_kernel<<<dim3(M_TOTAL / 64, D_MODEL / 64), 256, 0, stream>>>(
        Cc, Wob, bo, (float*)d_out);
}

// Round 11
// 180.982 us; speedup vs baseline: 1.4355x; 1.1929x over previous
//
#include <hip/hip_runtime.h>
#include <hip/hip_bf16.h>
#include <stdint.h>

typedef __bf16 bf16x8 __attribute__((ext_vector_type(8)));
typedef __bf16 bf16x4 __attribute__((ext_vector_type(4)));
typedef float  f32x4  __attribute__((ext_vector_type(4)));
typedef unsigned int u32x4 __attribute__((ext_vector_type(4)));

#define D_MODEL 1024
#define NUM_HEADS 16
#define D_K 64
#define BATCH 2
#define SEQ 2048
#define M_TOTAL (BATCH * SEQ)   // 4096

// 0.125 (1/sqrt(64)) * log2(e): folded into Q at the qkv epilogue so the
// attention softmax is a bare exp2 (v_exp_f32), no per-element scale mul.
#define Q_SCALE 0.18033688011112042f

static __device__ __forceinline__ bf16x8 load8(const __bf16* p) {
    return *reinterpret_cast<const bf16x8*>(p);
}

#define MFMA16(a, b, c) __builtin_amdgcn_mfma_f32_16x16x32_bf16((a), (b), (c), 0, 0, 0)

// Async global->LDS, 16B per lane. LDS dest = wave-uniform base + lane*16.
static __device__ __forceinline__ void gload16(const void* g, const void* lds) {
    __builtin_amdgcn_global_load_lds(
        (const __attribute__((address_space(1))) uint32_t*)g,
        (__attribute__((address_space(3))) uint32_t*)lds,
        16, 0, 0);
}

// Pack two f32 -> one u32 of 2 bf16 (lo = first arg). No builtin on gfx950.
static __device__ __forceinline__ uint32_t cvtpk(float lo, float hi) {
    uint32_t r;
    asm("v_cvt_pk_bf16_f32 %0, %1, %2" : "=v"(r) : "v"(lo), "v"(hi));
    return r;
}
// CDNA4 zip semantics ("DST rows 2:3 <-> SRC rows 0:1", rows = 16 lanes):
//   swap32: a' = (a@q0, a@q1, b@q0, b@q1), b' = (a@q2, a@q3, b@q2, b@q3)
static __device__ __forceinline__ void swap32(uint32_t& a, uint32_t& b) {
    asm("v_permlane32_swap_b32 %0, %1" : "+v"(a), "+v"(b));
}
// swap16 ("DST odd rows <-> SRC even rows"):
//   a' = (a@q0, b@q0, a@q2, b@q2), b' = (a@q1, b@q1, a@q3, b@q3)
static __device__ __forceinline__ void swap16(uint32_t& a, uint32_t& b) {
    asm("v_permlane16_swap_b32 %0, %1" : "+v"(a), "+v"(b));
}

// ---------------------------------------------------------------------------
// One launch: x (2048 blocks) + 4 weight matrices (512 blocks each) fp32->bf16.
// ---------------------------------------------------------------------------
__global__ __launch_bounds__(256) void convert_all(
    const float* __restrict__ X,
    const float* __restrict__ Wq, const float* __restrict__ Wk,
    const float* __restrict__ Wv, const float* __restrict__ Wo,
    __bf16* __restrict__ xb,
    __bf16* __restrict__ dq, __bf16* __restrict__ dk,
    __bf16* __restrict__ dv, __bf16* __restrict__ dw)
{
    const float* src; __bf16* dst; size_t idx;
    if (blockIdx.x < 2048) {
        src = X; dst = xb;
        idx = (size_t)blockIdx.x * 256 + threadIdx.x;
    } else {
        const int wb  = blockIdx.x - 2048;
        const int sel = wb >> 9;
        src = (sel == 0) ? Wq : (sel == 1) ? Wk : (sel == 2) ? Wv : Wo;
        dst = (sel == 0) ? dq : (sel == 1) ? dk : (sel == 2) ? dv : dw;
        idx = (size_t)(wb & 511) * 256 + threadIdx.x;
    }
    const f32x4 a = *reinterpret_cast<const f32x4*>(src + idx * 8);
    const f32x4 b = *reinterpret_cast<const f32x4*>(src + idx * 8 + 4);
    bf16x8 r;
#pragma unroll
    for (int e = 0; e < 4; e++) { r[e] = (__bf16)a[e]; r[4 + e] = (__bf16)b[e]; }
    *reinterpret_cast<bf16x8*>(dst + idx * 8) = r;
}

// ---------------------------------------------------------------------------
// QKV GEMM (R16 config): 128x128 tile, BK=64, swizzled gload16 staging,
// double-buffered prefetch loop (one barrier per K-step, next tile's loads
// in flight through compute). LDS 64 KB -> 2 blocks/CU. Q output pre-scaled
// by Q_SCALE. V transposed through LDS -> V^T. grid = (32, 24).
// ---------------------------------------------------------------------------
__global__ __launch_bounds__(256) void qkv_kernel(
    const __bf16* __restrict__ Xb,
    const __bf16* __restrict__ Wqb,
    const __bf16* __restrict__ Wkb,
    const __bf16* __restrict__ Wvb,
    __bf16* __restrict__ Qb,
    __bf16* __restrict__ Kb,
    __bf16* __restrict__ Vtg)
{
    __shared__ alignas(16) char smem[65536];   // A[2]16K + B[2]16K; V scratch 34K
    __bf16* As0 = (__bf16*)smem;               // [2][128*64], chunk-swizzled
    __bf16* Bs0 = As0 + 2 * 128 * 64;

    const int lane = threadIdx.x & 63;
    const int wid  = threadIdx.x >> 6;
    const int m    = lane & 15;
    const int quad = lane >> 4;
    const int wrow = wid >> 1, wcol = wid & 1;
    const int row0 = blockIdx.x * 128;
    const int col0 = blockIdx.y * 128;
    const int wsel = col0 >> 10;
    const int lcol0 = col0 & 1023;

    const __bf16* W = (wsel == 0) ? Wqb : (wsel == 1) ? Wkb : Wvb;

    // staging: 128x64 A-tile + 128x64 B-tile into buffer `buf`
    auto stage = [&](int k0, int buf) {
#pragma unroll
        for (int i = 0; i < 4; i++) {
            const int slot = wid * 256 + i * 64 + lane;
            const int row  = slot >> 3;
            const int cg   = (slot & 7) ^ (row & 7);
            gload16(Xb + (size_t)(row0 + row) * D_MODEL + k0 + cg * 8,
                    (const char*)(As0 + buf * 8192) + (size_t)(wid * 256 + i * 64) * 16);
            gload16(W + (size_t)(lcol0 + row) * D_MODEL + k0 + cg * 8,
                    (const char*)(Bs0 + buf * 8192) + (size_t)(wid * 256 + i * 64) * 16);
        }
    };

    f32x4 acc[4][4];
#pragma unroll
    for (int i = 0; i < 4; i++)
#pragma unroll
        for (int j = 0; j < 4; j++) acc[i][j] = (f32x4){0.f, 0.f, 0.f, 0.f};

    stage(0, 0);
    int cur = 0;
#pragma unroll 1
    for (int k0 = 0; k0 < D_MODEL; k0 += 64) {
        __syncthreads();                       // buffer `cur` staged
        if (k0 + 64 < D_MODEL) stage(k0 + 64, cur ^ 1);   // in flight through
                                                          // compute below
        const __bf16* As = As0 + cur * 8192;
        const __bf16* Bs = Bs0 + cur * 8192;

        bf16x8 a2[2][4], b2[2][4];
#pragma unroll
        for (int ks = 0; ks < 2; ks++) {
#pragma unroll
            for (int i = 0; i < 4; i++) {
                const int rA = wrow * 64 + i * 16 + m;
                a2[ks][i] = load8(As + rA * 64 + (((ks * 4 + quad) ^ (rA & 7)) * 8));
                const int rB = wcol * 64 + i * 16 + m;
                b2[ks][i] = load8(Bs + rB * 64 + (((ks * 4 + quad) ^ (rB & 7)) * 8));
            }
        }
#pragma unroll
        for (int ks = 0; ks < 2; ks++)
#pragma unroll
            for (int i = 0; i < 4; i++)
#pragma unroll
                for (int j = 0; j < 4; j++)
                    acc[i][j] = MFMA16(a2[ks][i], b2[ks][j], acc[i][j]);
        cur ^= 1;
    }
    __syncthreads();   // all LDS reads done before V-path smem reuse

    if (wsel < 2) {
        // Q (pre-scaled) / K: [bh][s][dk]
        __bf16* Out = wsel ? Kb : Qb;
        const float sc = wsel ? 1.f : Q_SCALE;
#pragma unroll
        for (int i = 0; i < 4; i++) {
#pragma unroll
            for (int r = 0; r < 4; r++) {
                const int R  = row0 + wrow * 64 + i * 16 + quad * 4 + r;
                const int bb = R >> 11;
                const int s  = R & (SEQ - 1);
#pragma unroll
                for (int j = 0; j < 4; j++) {
                    const int e  = lcol0 + wcol * 64 + j * 16 + m;
                    const int h  = e >> 6;
                    const int dk = e & (D_K - 1);
                    Out[((size_t)(bb * NUM_HEADS + h) * SEQ + s) * D_K + dk] =
                        (__bf16)(acc[i][j][r] * sc);
                }
            }
        }
    } else {
        // V: transpose tile through LDS, store coalesced V^T rows.
        __bf16* Ls = (__bf16*)smem;   // [128][136]
#pragma unroll
        for (int i = 0; i < 4; i++)
#pragma unroll
            for (int r = 0; r < 4; r++)
#pragma unroll
                for (int j = 0; j < 4; j++)
                    Ls[(wcol * 64 + j * 16 + m) * 136 +
                       wrow * 64 + i * 16 + quad * 4 + r] = (__bf16)acc[i][j][r];
        __syncthreads();
        const int bb   = row0 >> 11;
        const int sloc = row0 & (SEQ - 1);
#pragma unroll
        for (int i = 0; i < 8; i++) {
            const int c   = i * 256 + threadIdx.x;
            const int dkl = c >> 4;
            const int sc  = c & 15;
            const bf16x8 v = load8(Ls + dkl * 136 + sc * 8);
            const int e  = lcol0 + dkl;
            const int h  = e >> 6;
            const int dk = e & (D_K - 1);
            const int bh = bb * NUM_HEADS + h;
            *reinterpret_cast<bf16x8*>(
                Vtg + ((size_t)bh * D_K + dk) * SEQ + sloc + sc * 8) = v;
        }
    }
}

// ---------------------------------------------------------------------------
// Flash attention, causal, ONE STRIP PER BLOCK + DOUBLE-BUFFERED K/V LDS
// staging (R16 compute, verified 44.3 us/dispatch). R21: XCD-aware HEAD
// CLUSTERING (T1). Default dispatch round-robins consecutive blocks
// (different heads, sharing nothing) across XCDs -> per-XCD K/V working set
// 32 heads x 512 KB = 16 MB >> 4 MB L2. New map over linear id l:
//   bh = (l&7)*4 + ((l>>3)&3),  s = 31 - (l>>5)
// (bijective) -> XCD x serves only heads 4x..4x+3: 2 MB working set, L2-fit;
// staging loads become L2 hits (~200 cyc vs 600-900), shrinking the barrier
// drain of this latency-bound kernel. Big strips still dispatch first.
// R18/R19/R20 lesson kept: gload16->LDS->fragments for all reused operands.
// Register-resident P (zip-permlane), ones-MFMA row sums.
// ---------------------------------------------------------------------------
__global__ __launch_bounds__(256) void attn_kernel(
    const __bf16* __restrict__ Qb,
    const __bf16* __restrict__ Kb,
    const __bf16* __restrict__ Vtg,
    __bf16* __restrict__ Cc)
{
    __shared__ alignas(16) __bf16 Ks[2][64 * 64];  // ping-pong, 16 KB
    __shared__ alignas(16) __bf16 Vt[2][64 * 64];  // ping-pong, 16 KB

    const int lane = threadIdx.x & 63;
    const int wid  = threadIdx.x >> 6;
    const int m    = lane & 15;
    const int quad = lane >> 4;
    // XCD-aware head clustering: xcd = l%8 serves heads 4x..4x+3 only.
    const int l    = blockIdx.x + 32 * blockIdx.y;
    const int bh   = (l & 7) * 4 + ((l >> 3) & 3);
    const int s    = 31 - (l >> 5);                // strip index, big first
    const int b    = bh >> 4;
    const int h    = bh & (NUM_HEADS - 1);

    const __bf16* Qp = Qb  + (size_t)bh * SEQ * D_K;
    const __bf16* Kp = Kb  + (size_t)bh * SEQ * D_K;
    const __bf16* Vp = Vtg + (size_t)bh * D_K * SEQ;

    // staging lambda: 64x64 K tile + 64x64 V^T tile into buffer `buf`
    auto stage = [&](int k0, int buf) {
#pragma unroll
        for (int i = 0; i < 2; i++) {
            const int slot = wid * 128 + i * 64 + lane;
            const int row  = slot >> 3;
            const int cg   = (slot & 7) ^ (row & 7);
            gload16(Kp + (size_t)(k0 + row) * D_K + cg * 8,
                    (const char*)&Ks[buf][0] + (size_t)(wid * 128 + i * 64) * 16);
            gload16(Vp + (size_t)row * SEQ + k0 + cg * 8,
                    (const char*)&Vt[buf][0] + (size_t)(wid * 128 + i * 64) * 16);
        }
    };

    bf16x8 vone;
#pragma unroll
    for (int e = 0; e < 8; e++) vone[e] = (__bf16)1.0f;

    const int q0 = s * 64 + wid * 16;              // this wave's 16 q rows

    const bf16x8 qB0 = load8(Qp + (size_t)(q0 + m) * D_K + quad * 8);
    const bf16x8 qB1 = load8(Qp + (size_t)(q0 + m) * D_K + 32 + quad * 8);

    f32x4 oacc[4];
#pragma unroll
    for (int c = 0; c < 4; c++) oacc[c] = (f32x4){0.f, 0.f, 0.f, 0.f};
    f32x4 accL = (f32x4){0.f, 0.f, 0.f, 0.f};      // l for q = q0+quad*4+r

    stage(0, 0);
    int cur = 0;
#pragma unroll 1
    for (int t = 0; t <= s; t++) {
        __syncthreads();             // tile t's staging complete
        if (t < s) stage((t + 1) * 64, cur ^ 1);   // prefetch: in flight
                                                   // through compute below
        const bool diag = (t == s);
        const int  k0   = t * 64;
        const __bf16* Kc = &Ks[cur][0];
        const __bf16* Vc = &Vt[cur][0];

        // ---- S^T = K Q^T (rows=keys, cols=q); exp2; pack to bf16 words.
        // Lane (m,quad) produces keys {kb*16+quad*4 .. +3} for q=q0+m:
        // w0[kb] = keys {4*quad, 4*quad+1}, w1[kb] = {4*quad+2, 4*quad+3}.
        uint32_t w0[4], w1[4];
#pragma unroll
        for (int kb = 0; kb < 4; kb++) {
            const int rK = kb * 16 + m;
            const bf16x8 kfA = load8(Kc + rK * 64 + ((quad ^ (rK & 7)) * 8));
            const bf16x8 kfB = load8(Kc + rK * 64 + (((quad + 4) ^ (rK & 7)) * 8));
            f32x4 st = (f32x4){0.f, 0.f, 0.f, 0.f};
            st = MFMA16(kfA, qB0, st);
            st = MFMA16(kfB, qB1, st);
            const int q    = q0 + m;
            const int keyb = k0 + kb * 16 + quad * 4;
            float ex[4];
#pragma unroll
            for (int r = 0; r < 4; r++) {
                float e = __builtin_amdgcn_exp2f(st[r]);
                if (diag) e = (keyb + r <= q) ? e : 0.f;
                ex[r] = e;
            }
            w0[kb] = cvtpk(ex[0], ex[1]);
            w1[kb] = cvtpk(ex[2], ex[3]);
        }

        // ---- redistribute to A-fragments (keys 8*quad..+7 per lane).
        // Zip semantics, verified key-by-key:
        //   (X=w[lo], Y=w[hi]); swap32; swap16 => X=word j, Y=word j+2.
        uint32_t pa0 = w0[0], pa2 = w0[1]; swap32(pa0, pa2); swap16(pa0, pa2);
        uint32_t pa1 = w1[0], pa3 = w1[1]; swap32(pa1, pa3); swap16(pa1, pa3);
        uint32_t pb0 = w0[2], pb2 = w0[3]; swap32(pb0, pb2); swap16(pb0, pb2);
        uint32_t pb1 = w1[2], pb3 = w1[3]; swap32(pb1, pb3); swap16(pb1, pb3);
        const u32x4 ua = (u32x4){pa0, pa1, pa2, pa3};
        const u32x4 ub = (u32x4){pb0, pb1, pb2, pb3};
        const bf16x8 pfA = __builtin_bit_cast(bf16x8, ua);
        const bf16x8 pfB = __builtin_bit_cast(bf16x8, ub);

        // ---- row-sum via ones-MFMA: accL[r] = sum_k P[q=quad*4+r][k]
        accL = MFMA16(pfA, vone, accL);
        accL = MFMA16(pfB, vone, accL);

        // ---- P.V ----
#pragma unroll
        for (int c = 0; c < 4; c++) {
            const int rV = c * 16 + m;
            const bf16x8 vfA = load8(Vc + rV * 64 + ((quad ^ (rV & 7)) * 8));
            const bf16x8 vfB = load8(Vc + rV * 64 + (((quad + 4) ^ (rV & 7)) * 8));
            oacc[c] = MFMA16(pfA, vfA, oacc[c]);
            oacc[c] = MFMA16(pfB, vfB, oacc[c]);
        }
        cur ^= 1;
    }

    // ---- epilogue: l is already per-register in accL ----
#pragma unroll
    for (int r = 0; r < 4; r++) {
        const float inv = 1.f / accL[r];
        const int srow = q0 + quad * 4 + r;
#pragma unroll
        for (int c = 0; c < 4; c++) {
            const size_t o2 = ((size_t)(b * SEQ + srow)) * D_MODEL + h * D_K + c * 16 + m;
            Cc[o2] = (__bf16)(oacc[c][r] * inv);
        }
    }
}

// ---------------------------------------------------------------------------
// Output projection (R16 config): Out = Cc * Wo^T + bo (fp32). 64x64 tile,
// grid (64,16) = 1024 blocks = 4/CU, double-buffered prefetch loop (one
// barrier per K-step), both operands via gload16 (bf16).
// ---------------------------------------------------------------------------
__global__ __launch_bounds__(256) void oproj_kernel(
    const __bf16* __restrict__ Cc,
    const __bf16* __restrict__ Wob,
    const float* __restrict__ bo,
    float* __restrict__ Out)
{
    __shared__ alignas(16) __bf16 As[2][64 * 64];  // ping-pong, 8 KB each
    __shared__ alignas(16) __bf16 Bs[2][64 * 64];  // ping-pong, 8 KB each

    const int lane = threadIdx.x & 63;
    const int wid  = threadIdx.x >> 6;
    const int m    = lane & 15;
    const int quad = lane >> 4;
    const int wrow = wid >> 1, wcol = wid & 1;
    const int row0 = blockIdx.x * 64;
    const int col0 = blockIdx.y * 64;

    auto stage = [&](int k0, int buf) {
#pragma unroll
        for (int i = 0; i < 2; i++) {
            const int slot = wid * 128 + i * 64 + lane;
            const int row  = slot >> 3;
            const int cg   = (slot & 7) ^ (row & 7);
            gload16(Cc + (size_t)(row0 + row) * D_MODEL + k0 + cg * 8,
                    (const char*)&As[buf][0] + (size_t)slot * 16);
            gload16(Wob + (size_t)(col0 + row) * D_MODEL + k0 + cg * 8,
                    (const char*)&Bs[buf][0] + (size_t)slot * 16);
        }
    };

    f32x4 acc[2][2];
#pragma unroll
    for (int i = 0; i < 2; i++)
#pragma unroll
        for (int j = 0; j < 2; j++) acc[i][j] = (f32x4){0.f, 0.f, 0.f, 0.f};

    stage(0, 0);
    int cur = 0;
#pragma unroll 1
    for (int k0 = 0; k0 < D_MODEL; k0 += 64) {
        __syncthreads();                       // buffer `cur` staged
        if (k0 + 64 < D_MODEL) stage(k0 + 64, cur ^ 1);

        bf16x8 a2[2][2], b2[2][2];
#pragma unroll
        for (int ks = 0; ks < 2; ks++) {
#pragma unroll
            for (int i = 0; i < 2; i++) {
                const int rA = wrow * 32 + i * 16 + m;
                a2[ks][i] = load8(&As[cur][0] + rA * 64 + (((ks * 4 + quad) ^ (rA & 7)) * 8));
                const int rB = wcol * 32 + i * 16 + m;
                b2[ks][i] = load8(&Bs[cur][0] + rB * 64 + (((ks * 4 + quad) ^ (rB & 7)) * 8));
            }
        }
#pragma unroll
        for (int ks = 0; ks < 2; ks++)
#pragma unroll
            for (int i = 0; i < 2; i++)
#pragma unroll
                for (int j = 0; j < 2; j++)
                    acc[i][j] = MFMA16(a2[ks][i], b2[ks][j], acc[i][j]);
        cur ^= 1;
    }

#pragma unroll
    for (int i = 0; i < 2; i++) {
#pragma unroll
        for (int r = 0; r < 4; r++) {
            const int R = row0 + wrow * 32 + i * 16 + quad * 4 + r;
#pragma unroll
            for (int j = 0; j < 2; j++) {
                const int E = col0 + wcol * 32 + j * 16 + m;
                Out[(size_t)R * D_MODEL + E] = acc[i][j][r] + bo[E];
            }
        }
    }
}

// ---------------------------------------------------------------------------
extern "C" void kernel_launch(void* const* d_in, const int* in_sizes, int n_in,
                              void* d_out, int out_size, void* d_ws, size_t ws_size,
                              hipStream_t stream) {
    const float* x  = (const float*)d_in[0];
    const float* Wq = (const float*)d_in[1];
    const float* Wk = (const float*)d_in[2];
    const float* Wv = (const float*)d_in[3];
    const float* Wo = (const float*)d_in[4];
    const float* bo = (const float*)d_in[5];
    // d_in[6] = causal mask — recomputed from indices, not read.

    const size_t elems  = (size_t)M_TOTAL * D_MODEL;   // 4194304
    const size_t welems = (size_t)D_MODEL * D_MODEL;   // 1048576
    __bf16* xb  = (__bf16*)d_ws;       // seg0: x (bf16) -> later Cc (aliased)
    __bf16* Qb  = xb + elems;
    __bf16* Kb  = Qb + elems;
    __bf16* Vtg = Kb + elems;          // [32][64][2048]  (V^T)
    __bf16* Wqb = Vtg + elems;
    __bf16* Wkb = Wqb + welems;
    __bf16* Wvb = Wkb + welems;
    __bf16* Wob = Wvb + welems;        // end: 40 MB
    __bf16* Cc  = xb;

    // 0) all fp32 -> bf16 conversions in one launch
    convert_all<<<dim3(4096), 256, 0, stream>>>(
        x, Wq, Wk, Wv, Wo, xb, Wqb, Wkb, Wvb, Wob);

    // 1) QKV projections (Q pre-scaled by 0.125*log2e), dbuf prefetch loop
    qkv_kernel<<<dim3(M_TOTAL / 128, 3 * D_MODEL / 128), 256, 0, stream>>>(
        xb, Wqb, Wkb, Wvb, Qb, Kb, Vtg);

    // 2) causal flash attention: XCD-aware head clustering (L2-fit K/V)
    attn_kernel<<<dim3(32, 32), 256, 0, stream>>>(
        Qb, Kb, Vtg, Cc);

    // 3) output projection + bias -> fp32 out (64x64 tiles, dbuf prefetch)
    oproj_kernel<<<dim3(M_TOTAL / 64, D_MODEL / 64), 256, 0, stream>>>(
        Cc, Wob, bo, (float*)d_out);
}

// Round 13
// 177.925 us; speedup vs baseline: 1.4602x; 1.0172x over previous
//
#include <hip/hip_runtime.h>
#include <hip/hip_bf16.h>
#include <stdint.h>

typedef __bf16 bf16x8 __attribute__((ext_vector_type(8)));
typedef __bf16 bf16x4 __attribute__((ext_vector_type(4)));
typedef float  f32x4  __attribute__((ext_vector_type(4)));
typedef unsigned int u32x4 __attribute__((ext_vector_type(4)));

#define D_MODEL 1024
#define NUM_HEADS 16
#define D_K 64
#define BATCH 2
#define SEQ 2048
#define M_TOTAL (BATCH * SEQ)   // 4096

// 0.125 (1/sqrt(64)) * log2(e): folded into Q at the qkv epilogue so the
// attention softmax is a bare exp2 (v_exp_f32), no per-element scale mul.
#define Q_SCALE 0.18033688011112042f

static __device__ __forceinline__ bf16x8 load8(const __bf16* p) {
    return *reinterpret_cast<const bf16x8*>(p);
}

#define MFMA16(a, b, c) __builtin_amdgcn_mfma_f32_16x16x32_bf16((a), (b), (c), 0, 0, 0)

// Async global->LDS, 16B per lane. LDS dest = wave-uniform base + lane*16.
static __device__ __forceinline__ void gload16(const void* g, const void* lds) {
    __builtin_amdgcn_global_load_lds(
        (const __attribute__((address_space(1))) uint32_t*)g,
        (__attribute__((address_space(3))) uint32_t*)lds,
        16, 0, 0);
}

// Pack two f32 -> one u32 of 2 bf16 (lo = first arg). No builtin on gfx950.
static __device__ __forceinline__ uint32_t cvtpk(float lo, float hi) {
    uint32_t r;
    asm("v_cvt_pk_bf16_f32 %0, %1, %2" : "=v"(r) : "v"(lo), "v"(hi));
    return r;
}
// CDNA4 zip semantics ("DST rows 2:3 <-> SRC rows 0:1", rows = 16 lanes):
//   swap32: a' = (a@q0, a@q1, b@q0, b@q1), b' = (a@q2, a@q3, b@q2, b@q3)
static __device__ __forceinline__ void swap32(uint32_t& a, uint32_t& b) {
    asm("v_permlane32_swap_b32 %0, %1" : "+v"(a), "+v"(b));
}
// swap16 ("DST odd rows <-> SRC even rows"):
//   a' = (a@q0, b@q0, a@q2, b@q2), b' = (a@q1, b@q1, a@q3, b@q3)
static __device__ __forceinline__ void swap16(uint32_t& a, uint32_t& b) {
    asm("v_permlane16_swap_b32 %0, %1" : "+v"(a), "+v"(b));
}

// ---------------------------------------------------------------------------
// One launch: x (2048 blocks) + 4 weight matrices (512 blocks each) fp32->bf16.
// ---------------------------------------------------------------------------
__global__ __launch_bounds__(256) void convert_all(
    const float* __restrict__ X,
    const float* __restrict__ Wq, const float* __restrict__ Wk,
    const float* __restrict__ Wv, const float* __restrict__ Wo,
    __bf16* __restrict__ xb,
    __bf16* __restrict__ dq, __bf16* __restrict__ dk,
    __bf16* __restrict__ dv, __bf16* __restrict__ dw)
{
    const float* src; __bf16* dst; size_t idx;
    if (blockIdx.x < 2048) {
        src = X; dst = xb;
        idx = (size_t)blockIdx.x * 256 + threadIdx.x;
    } else {
        const int wb  = blockIdx.x - 2048;
        const int sel = wb >> 9;
        src = (sel == 0) ? Wq : (sel == 1) ? Wk : (sel == 2) ? Wv : Wo;
        dst = (sel == 0) ? dq : (sel == 1) ? dk : (sel == 2) ? dv : dw;
        idx = (size_t)(wb & 511) * 256 + threadIdx.x;
    }
    const f32x4 a = *reinterpret_cast<const f32x4*>(src + idx * 8);
    const f32x4 b = *reinterpret_cast<const f32x4*>(src + idx * 8 + 4);
    bf16x8 r;
#pragma unroll
    for (int e = 0; e < 4; e++) { r[e] = (__bf16)a[e]; r[4 + e] = (__bf16)b[e]; }
    *reinterpret_cast<bf16x8*>(dst + idx * 8) = r;
}

// ---------------------------------------------------------------------------
// QKV GEMM (R16 config): 128x128 tile, BK=64, swizzled gload16 staging,
// double-buffered prefetch loop (one barrier per K-step, next tile's loads
// in flight through compute). LDS 64 KB -> 2 blocks/CU. Q output pre-scaled
// by Q_SCALE. V transposed through LDS -> V^T. grid = (32, 24).
// ---------------------------------------------------------------------------
__global__ __launch_bounds__(256) void qkv_kernel(
    const __bf16* __restrict__ Xb,
    const __bf16* __restrict__ Wqb,
    const __bf16* __restrict__ Wkb,
    const __bf16* __restrict__ Wvb,
    __bf16* __restrict__ Qb,
    __bf16* __restrict__ Kb,
    __bf16* __restrict__ Vtg)
{
    __shared__ alignas(16) char smem[65536];   // A[2]16K + B[2]16K; V scratch 34K
    __bf16* As0 = (__bf16*)smem;               // [2][128*64], chunk-swizzled
    __bf16* Bs0 = As0 + 2 * 128 * 64;

    const int lane = threadIdx.x & 63;
    const int wid  = threadIdx.x >> 6;
    const int m    = lane & 15;
    const int quad = lane >> 4;
    const int wrow = wid >> 1, wcol = wid & 1;
    const int row0 = blockIdx.x * 128;
    const int col0 = blockIdx.y * 128;
    const int wsel = col0 >> 10;
    const int lcol0 = col0 & 1023;

    const __bf16* W = (wsel == 0) ? Wqb : (wsel == 1) ? Wkb : Wvb;

    // staging: 128x64 A-tile + 128x64 B-tile into buffer `buf`
    auto stage = [&](int k0, int buf) {
#pragma unroll
        for (int i = 0; i < 4; i++) {
            const int slot = wid * 256 + i * 64 + lane;
            const int row  = slot >> 3;
            const int cg   = (slot & 7) ^ (row & 7);
            gload16(Xb + (size_t)(row0 + row) * D_MODEL + k0 + cg * 8,
                    (const char*)(As0 + buf * 8192) + (size_t)(wid * 256 + i * 64) * 16);
            gload16(W + (size_t)(lcol0 + row) * D_MODEL + k0 + cg * 8,
                    (const char*)(Bs0 + buf * 8192) + (size_t)(wid * 256 + i * 64) * 16);
        }
    };

    f32x4 acc[4][4];
#pragma unroll
    for (int i = 0; i < 4; i++)
#pragma unroll
        for (int j = 0; j < 4; j++) acc[i][j] = (f32x4){0.f, 0.f, 0.f, 0.f};

    stage(0, 0);
    int cur = 0;
#pragma unroll 1
    for (int k0 = 0; k0 < D_MODEL; k0 += 64) {
        __syncthreads();                       // buffer `cur` staged
        if (k0 + 64 < D_MODEL) stage(k0 + 64, cur ^ 1);   // in flight through
                                                          // compute below
        const __bf16* As = As0 + cur * 8192;
        const __bf16* Bs = Bs0 + cur * 8192;

        bf16x8 a2[2][4], b2[2][4];
#pragma unroll
        for (int ks = 0; ks < 2; ks++) {
#pragma unroll
            for (int i = 0; i < 4; i++) {
                const int rA = wrow * 64 + i * 16 + m;
                a2[ks][i] = load8(As + rA * 64 + (((ks * 4 + quad) ^ (rA & 7)) * 8));
                const int rB = wcol * 64 + i * 16 + m;
                b2[ks][i] = load8(Bs + rB * 64 + (((ks * 4 + quad) ^ (rB & 7)) * 8));
            }
        }
#pragma unroll
        for (int ks = 0; ks < 2; ks++)
#pragma unroll
            for (int i = 0; i < 4; i++)
#pragma unroll
                for (int j = 0; j < 4; j++)
                    acc[i][j] = MFMA16(a2[ks][i], b2[ks][j], acc[i][j]);
        cur ^= 1;
    }
    __syncthreads();   // all LDS reads done before V-path smem reuse

    if (wsel < 2) {
        // Q (pre-scaled) / K: [bh][s][dk]
        __bf16* Out = wsel ? Kb : Qb;
        const float sc = wsel ? 1.f : Q_SCALE;
#pragma unroll
        for (int i = 0; i < 4; i++) {
#pragma unroll
            for (int r = 0; r < 4; r++) {
                const int R  = row0 + wrow * 64 + i * 16 + quad * 4 + r;
                const int bb = R >> 11;
                const int s  = R & (SEQ - 1);
#pragma unroll
                for (int j = 0; j < 4; j++) {
                    const int e  = lcol0 + wcol * 64 + j * 16 + m;
                    const int h  = e >> 6;
                    const int dk = e & (D_K - 1);
                    Out[((size_t)(bb * NUM_HEADS + h) * SEQ + s) * D_K + dk] =
                        (__bf16)(acc[i][j][r] * sc);
                }
            }
        }
    } else {
        // V: transpose tile through LDS, store coalesced V^T rows.
        __bf16* Ls = (__bf16*)smem;   // [128][136]
#pragma unroll
        for (int i = 0; i < 4; i++)
#pragma unroll
            for (int r = 0; r < 4; r++)
#pragma unroll
                for (int j = 0; j < 4; j++)
                    Ls[(wcol * 64 + j * 16 + m) * 136 +
                       wrow * 64 + i * 16 + quad * 4 + r] = (__bf16)acc[i][j][r];
        __syncthreads();
        const int bb   = row0 >> 11;
        const int sloc = row0 & (SEQ - 1);
#pragma unroll
        for (int i = 0; i < 8; i++) {
            const int c   = i * 256 + threadIdx.x;
            const int dkl = c >> 4;
            const int sc  = c & 15;
            const bf16x8 v = load8(Ls + dkl * 136 + sc * 8);
            const int e  = lcol0 + dkl;
            const int h  = e >> 6;
            const int dk = e & (D_K - 1);
            const int bh = bb * NUM_HEADS + h;
            *reinterpret_cast<bf16x8*>(
                Vtg + ((size_t)bh * D_K + dk) * SEQ + sloc + sc * 8) = v;
        }
    }
}

// ---------------------------------------------------------------------------
// Flash attention, causal. R22 (resubmitted after R12 infra failure):
// 8-WAVE BLOCKS (512 threads), QBLK=128. Each wave owns 16 q-rows -- the
// per-wave inner code is byte-identical to the proven R16 kernel (chain
// length unchanged, R14's mistake avoided). One 64-key K/V tile staged per
// block-tile now serves 8 waves instead of 4: total tile-stagings 16896 ->
// 8704 (LDS fill 270 -> 139 MB) and per-CU barrier-drain events halve
// (66 -> 34). grid (32 bh, 16 strips) = 512 blocks = 2 blocks/CU = 16
// waves/CU (same wave count as R16's 4x4). Causal: wave's diagonal tile
// myDiag = q0>>6; waves skip compute (never the barrier) on tiles past
// their diagonal. Staging = 1 K-load + 1 V-load per thread (512 threads x
// 16 B = the 8 KB tile exactly). All threads reach all barriers (the
// t<=myDiag predicate guards compute only); stage() addresses in-bounds
// for every thread. Register-resident P (zip-permlane), ones-MFMA row sums.
// ---------------------------------------------------------------------------
__global__ __launch_bounds__(512) void attn_kernel(
    const __bf16* __restrict__ Qb,
    const __bf16* __restrict__ Kb,
    const __bf16* __restrict__ Vtg,
    __bf16* __restrict__ Cc)
{
    __shared__ alignas(16) __bf16 Ks[2][64 * 64];  // ping-pong, 16 KB
    __shared__ alignas(16) __bf16 Vt[2][64 * 64];  // ping-pong, 16 KB

    const int lane = threadIdx.x & 63;
    const int wid  = threadIdx.x >> 6;             // 0..7
    const int m    = lane & 15;
    const int quad = lane >> 4;
    const int bh   = blockIdx.x;
    const int b    = bh >> 4;
    const int h    = bh & (NUM_HEADS - 1);
    const int sp   = 15 - blockIdx.y;              // 128-row strip, big first

    const __bf16* Qp = Qb  + (size_t)bh * SEQ * D_K;
    const __bf16* Kp = Kb  + (size_t)bh * SEQ * D_K;
    const __bf16* Vp = Vtg + (size_t)bh * D_K * SEQ;

    // staging: 64x64 K tile + 64x64 V^T tile; 512 threads cover each 8 KB
    // tile in ONE gload16 per thread per operand.
    auto stage = [&](int k0, int buf) {
        const int slot = wid * 64 + lane;
        const int row  = slot >> 3;
        const int cg   = (slot & 7) ^ (row & 7);
        gload16(Kp + (size_t)(k0 + row) * D_K + cg * 8,
                (const char*)&Ks[buf][0] + (size_t)slot * 16);
        gload16(Vp + (size_t)row * SEQ + k0 + cg * 8,
                (const char*)&Vt[buf][0] + (size_t)slot * 16);
    };

    bf16x8 vone;
#pragma unroll
    for (int e = 0; e < 8; e++) vone[e] = (__bf16)1.0f;

    const int q0     = sp * 128 + wid * 16;        // this wave's 16 q rows
    const int myDiag = q0 >> 6;                    // wave's diagonal tile
    const int T      = 2 * sp + 2;                 // tiles for this strip

    const bf16x8 qB0 = load8(Qp + (size_t)(q0 + m) * D_K + quad * 8);
    const bf16x8 qB1 = load8(Qp + (size_t)(q0 + m) * D_K + 32 + quad * 8);

    f32x4 oacc[4];
#pragma unroll
    for (int c = 0; c < 4; c++) oacc[c] = (f32x4){0.f, 0.f, 0.f, 0.f};
    f32x4 accL = (f32x4){0.f, 0.f, 0.f, 0.f};      // l for q = q0+quad*4+r

    stage(0, 0);
    int cur = 0;
#pragma unroll 1
    for (int t = 0; t < T; t++) {
        __syncthreads();             // tile t's staging complete (all waves)
        if (t + 1 < T) stage((t + 1) * 64, cur ^ 1);   // prefetch: in flight
                                                       // through compute below
        if (t <= myDiag) {
            const bool diag = (t == myDiag);
            const int  k0   = t * 64;
            const __bf16* Kc = &Ks[cur][0];
            const __bf16* Vc = &Vt[cur][0];

            // ---- S^T = K Q^T (rows=keys, cols=q); exp2; pack to bf16.
            // Lane (m,quad) produces keys {kb*16+quad*4 .. +3} for q=q0+m:
            // w0[kb] = keys {4*quad, 4*quad+1}, w1[kb] = {+2, +3}.
            uint32_t w0[4], w1[4];
#pragma unroll
            for (int kb = 0; kb < 4; kb++) {
                const int rK = kb * 16 + m;
                const bf16x8 kfA = load8(Kc + rK * 64 + ((quad ^ (rK & 7)) * 8));
                const bf16x8 kfB = load8(Kc + rK * 64 + (((quad + 4) ^ (rK & 7)) * 8));
                f32x4 st = (f32x4){0.f, 0.f, 0.f, 0.f};
                st = MFMA16(kfA, qB0, st);
                st = MFMA16(kfB, qB1, st);
                const int q    = q0 + m;
                const int keyb = k0 + kb * 16 + quad * 4;
                float ex[4];
#pragma unroll
                for (int r = 0; r < 4; r++) {
                    float e = __builtin_amdgcn_exp2f(st[r]);
                    if (diag) e = (keyb + r <= q) ? e : 0.f;
                    ex[r] = e;
                }
                w0[kb] = cvtpk(ex[0], ex[1]);
                w1[kb] = cvtpk(ex[2], ex[3]);
            }

            // ---- redistribute to A-fragments (keys 8*quad..+7 per lane).
            // Zip semantics, verified key-by-key:
            //   (X=w[lo], Y=w[hi]); swap32; swap16 => X=word j, Y=word j+2.
            uint32_t pa0 = w0[0], pa2 = w0[1]; swap32(pa0, pa2); swap16(pa0, pa2);
            uint32_t pa1 = w1[0], pa3 = w1[1]; swap32(pa1, pa3); swap16(pa1, pa3);
            uint32_t pb0 = w0[2], pb2 = w0[3]; swap32(pb0, pb2); swap16(pb0, pb2);
            uint32_t pb1 = w1[2], pb3 = w1[3]; swap32(pb1, pb3); swap16(pb1, pb3);
            const u32x4 ua = (u32x4){pa0, pa1, pa2, pa3};
            const u32x4 ub = (u32x4){pb0, pb1, pb2, pb3};
            const bf16x8 pfA = __builtin_bit_cast(bf16x8, ua);
            const bf16x8 pfB = __builtin_bit_cast(bf16x8, ub);

            // ---- row-sum via ones-MFMA: accL[r] = sum_k P[q=quad*4+r][k]
            accL = MFMA16(pfA, vone, accL);
            accL = MFMA16(pfB, vone, accL);

            // ---- P.V ----
#pragma unroll
            for (int c = 0; c < 4; c++) {
                const int rV = c * 16 + m;
                const bf16x8 vfA = load8(Vc + rV * 64 + ((quad ^ (rV & 7)) * 8));
                const bf16x8 vfB = load8(Vc + rV * 64 + (((quad + 4) ^ (rV & 7)) * 8));
                oacc[c] = MFMA16(pfA, vfA, oacc[c]);
                oacc[c] = MFMA16(pfB, vfB, oacc[c]);
            }
        }
        cur ^= 1;
    }

    // ---- epilogue: l is already per-register in accL ----
#pragma unroll
    for (int r = 0; r < 4; r++) {
        const float inv = 1.f / accL[r];
        const int srow = q0 + quad * 4 + r;
#pragma unroll
        for (int c = 0; c < 4; c++) {
            const size_t o2 = ((size_t)(b * SEQ + srow)) * D_MODEL + h * D_K + c * 16 + m;
            Cc[o2] = (__bf16)(oacc[c][r] * inv);
        }
    }
}

// ---------------------------------------------------------------------------
// Output projection (R16 config): Out = Cc * Wo^T + bo (fp32). 64x64 tile,
// grid (64,16) = 1024 blocks = 4/CU, double-buffered prefetch loop (one
// barrier per K-step), both operands via gload16 (bf16).
// ---------------------------------------------------------------------------
__global__ __launch_bounds__(256) void oproj_kernel(
    const __bf16* __restrict__ Cc,
    const __bf16* __restrict__ Wob,
    const float* __restrict__ bo,
    float* __restrict__ Out)
{
    __shared__ alignas(16) __bf16 As[2][64 * 64];  // ping-pong, 8 KB each
    __shared__ alignas(16) __bf16 Bs[2][64 * 64];  // ping-pong, 8 KB each

    const int lane = threadIdx.x & 63;
    const int wid  = threadIdx.x >> 6;
    const int m    = lane & 15;
    const int quad = lane >> 4;
    const int wrow = wid >> 1, wcol = wid & 1;
    const int row0 = blockIdx.x * 64;
    const int col0 = blockIdx.y * 64;

    auto stage = [&](int k0, int buf) {
#pragma unroll
        for (int i = 0; i < 2; i++) {
            const int slot = wid * 128 + i * 64 + lane;
            const int row  = slot >> 3;
            const int cg   = (slot & 7) ^ (row & 7);
            gload16(Cc + (size_t)(row0 + row) * D_MODEL + k0 + cg * 8,
                    (const char*)&As[buf][0] + (size_t)slot * 16);
            gload16(Wob + (size_t)(col0 + row) * D_MODEL + k0 + cg * 8,
                    (const char*)&Bs[buf][0] + (size_t)slot * 16);
        }
    };

    f32x4 acc[2][2];
#pragma unroll
    for (int i = 0; i < 2; i++)
#pragma unroll
        for (int j = 0; j < 2; j++) acc[i][j] = (f32x4){0.f, 0.f, 0.f, 0.f};

    stage(0, 0);
    int cur = 0;
#pragma unroll 1
    for (int k0 = 0; k0 < D_MODEL; k0 += 64) {
        __syncthreads();                       // buffer `cur` staged
        if (k0 + 64 < D_MODEL) stage(k0 + 64, cur ^ 1);

        bf16x8 a2[2][2], b2[2][2];
#pragma unroll
        for (int ks = 0; ks < 2; ks++) {
#pragma unroll
            for (int i = 0; i < 2; i++) {
                const int rA = wrow * 32 + i * 16 + m;
                a2[ks][i] = load8(&As[cur][0] + rA * 64 + (((ks * 4 + quad) ^ (rA & 7)) * 8));
                const int rB = wcol * 32 + i * 16 + m;
                b2[ks][i] = load8(&Bs[cur][0] + rB * 64 + (((ks * 4 + quad) ^ (rB & 7)) * 8));
            }
        }
#pragma unroll
        for (int ks = 0; ks < 2; ks++)
#pragma unroll
            for (int i = 0; i < 2; i++)
#pragma unroll
                for (int j = 0; j < 2; j++)
                    acc[i][j] = MFMA16(a2[ks][i], b2[ks][j], acc[i][j]);
        cur ^= 1;
    }

#pragma unroll
    for (int i = 0; i < 2; i++) {
#pragma unroll
        for (int r = 0; r < 4; r++) {
            const int R = row0 + wrow * 32 + i * 16 + quad * 4 + r;
#pragma unroll
            for (int j = 0; j < 2; j++) {
                const int E = col0 + wcol * 32 + j * 16 + m;
                Out[(size_t)R * D_MODEL + E] = acc[i][j][r] + bo[E];
            }
        }
    }
}

// ---------------------------------------------------------------------------
extern "C" void kernel_launch(void* const* d_in, const int* in_sizes, int n_in,
                              void* d_out, int out_size, void* d_ws, size_t ws_size,
                              hipStream_t stream) {
    const float* x  = (const float*)d_in[0];
    const float* Wq = (const float*)d_in[1];
    const float* Wk = (const float*)d_in[2];
    const float* Wv = (const float*)d_in[3];
    const float* Wo = (const float*)d_in[4];
    const float* bo = (const float*)d_in[5];
    // d_in[6] = causal mask — recomputed from indices, not read.

    const size_t elems  = (size_t)M_TOTAL * D_MODEL;   // 4194304
    const size_t welems = (size_t)D_MODEL * D_MODEL;   // 1048576
    __bf16* xb  = (__bf16*)d_ws;       // seg0: x (bf16) -> later Cc (aliased)
    __bf16* Qb  = xb + elems;
    __bf16* Kb  = Qb + elems;
    __bf16* Vtg = Kb + elems;          // [32][64][2048]  (V^T)
    __bf16* Wqb = Vtg + elems;
    __bf16* Wkb = Wqb + welems;
    __bf16* Wvb = Wkb + welems;
    __bf16* Wob = Wvb + welems;        // end: 40 MB
    __bf16* Cc  = xb;

    // 0) all fp32 -> bf16 conversions in one launch
    convert_all<<<dim3(4096), 256, 0, stream>>>(
        x, Wq, Wk, Wv, Wo, xb, Wqb, Wkb, Wvb, Wob);

    // 1) QKV projections (Q pre-scaled by 0.125*log2e), dbuf prefetch loop
    qkv_kernel<<<dim3(M_TOTAL / 128, 3 * D_MODEL / 128), 256, 0, stream>>>(
        xb, Wqb, Wkb, Wvb, Qb, Kb, Vtg);

    // 2) causal flash attention: 8-wave blocks, QBLK=128, half the barriers
    attn_kernel<<<dim3(BATCH * NUM_HEADS, 16), 512, 0, stream>>>(
        Qb, Kb, Vtg, Cc);

    // 3) output projection + bias -> fp32 out (64x64 tiles, dbuf prefetch)
    oproj_kernel<<<dim3(M_TOTAL / 64, D_MODEL / 64), 256, 0, stream>>>(
        Cc, Wob, bo, (float*)d_out);
}